// Round 1
// 662.595 us; speedup vs baseline: 1.0723x; 1.0723x over previous
//
#include <hip/hip_runtime.h>
#include <math.h>

// Problem constants: B=8, C=256, H=W=128
#define PIX 16384                       // H*W
#define TSZ ((size_t)33554432)          // 8*256*16384 elements per tensor

typedef __attribute__((ext_vector_type(8))) short  short8;   // 8 x bf16 (4 VGPRs)
typedef __attribute__((ext_vector_type(4))) float  float4v;
typedef __attribute__((ext_vector_type(4))) unsigned int uint4v;
typedef __attribute__((ext_vector_type(2))) unsigned int uint2v;

__device__ __forceinline__ unsigned short f2bf(float x) {
  unsigned int u = __float_as_uint(x);
  u += 0x7fffu + ((u >> 16) & 1u);      // round-to-nearest-even
  return (unsigned short)(u >> 16);
}
__device__ __forceinline__ float bf2f(unsigned short h) {
  return __uint_as_float(((unsigned int)h) << 16);
}
// pack two fp32 -> (bf16(hi)<<16)|bf16(lo) via v_perm_b32
__device__ __forceinline__ unsigned int pack_bf2(float lo, float hi) {
  unsigned int ul = __float_as_uint(lo); ul += 0x7fffu + ((ul >> 16) & 1u);
  unsigned int uh = __float_as_uint(hi); uh += 0x7fffu + ((uh >> 16) & 1u);
  return __builtin_amdgcn_perm(uh, ul, 0x07060302u);  // [ul.b2,ul.b3,uh.b2,uh.b3]
}

// ---------------------------------------------------------------------------
// Kernel 0: convert the four 256x256 weight matrices to bf16.
// Conv order: 0=FF(wf), 1=GG(wg), 2=EE(we), 3=HH(wh)
// ---------------------------------------------------------------------------
__global__ __launch_bounds__(256) void k_prep(const float* __restrict__ we,
                                              const float* __restrict__ wf,
                                              const float* __restrict__ wg,
                                              const float* __restrict__ wh,
                                              unsigned short* __restrict__ wbf) {
  int idx = blockIdx.x * 256 + threadIdx.x;      // 0 .. 262143
  int which = idx >> 16, off = idx & 65535;
  const float* src = (which == 0) ? wf : (which == 1) ? wg : (which == 2) ? we : wh;
  wbf[idx] = f2bf(src[off]);
}

// ---------------------------------------------------------------------------
// Kernel 1: 7x7 patch stats (zero-padded box sums), normalization, adain.
// (unchanged this round)
// ---------------------------------------------------------------------------
__global__ __launch_bounds__(256, 4) void k_stats(const float* __restrict__ front,
                                                  const float* __restrict__ back,
                                                  unsigned short* __restrict__ xcm) {
  int blk = blockIdx.x;
  int s   = blk & 7;            // strip (16 rows)
  int c   = (blk >> 3) & 255;
  int b   = blk >> 11;
  int t   = threadIdx.x;
  int r0  = s * 16;

  __shared__ float  xs[22 * 129];
  __shared__ float2 vsp[16 * 131];
  __shared__ unsigned long long obI[16 * 64];

  size_t planeOff = ((size_t)(b * 256 + c)) * PIX;

  float meanR[8], sdR[8];       // back stats, phase0 -> phase1 carry

  #pragma unroll 1
  for (int phase = 0; phase < 2; ++phase) {     // 0 = back, 1 = front
    const float* src = (phase == 0 ? back : front) + planeOff;
    #pragma unroll
    for (int i = 0; i < 3; ++i) {
      int idx = t + i * 256;                     // 704 = 22*32 float4s
      if (idx < 704) {
        int l = idx >> 5, cv = (idx & 31) * 4;
        int g = r0 - 3 + l;
        float4v v = {0.f, 0.f, 0.f, 0.f};
        if (g >= 0 && g < 128) v = *(const float4v*)(src + g * 128 + cv);
        xs[l * 129 + cv]     = v[0];
        xs[l * 129 + cv + 1] = v[1];
        xs[l * 129 + cv + 2] = v[2];
        xs[l * 129 + cv + 3] = v[3];
      }
    }
    __syncthreads();
    {
      int col = t & 127;
      int rg  = (t >> 7) * 8;                    // 8 output rows per thread
      float sm = 0.f, s2 = 0.f;
      #pragma unroll
      for (int j = 0; j < 7; ++j) { float v = xs[(rg + j) * 129 + col]; sm += v; s2 = fmaf(v, v, s2); }
      vsp[rg * 131 + col] = make_float2(sm, s2);
      #pragma unroll
      for (int o = 1; o < 8; ++o) {
        float vn = xs[(rg + o + 6) * 129 + col];
        float vo = xs[(rg + o - 1) * 129 + col];
        sm += vn - vo;
        s2 += vn * vn - vo * vo;
        vsp[(rg + o) * 131 + col] = make_float2(sm, s2);
      }
    }
    __syncthreads();
    {
      int r  = t & 15;
      int c0 = (t >> 4) * 8;                     // 8 output cols per thread
      float2 w[14];
      #pragma unroll
      for (int i = 0; i < 14; ++i) {
        int cc = c0 - 3 + i;
        float2 v = make_float2(0.f, 0.f);
        if (cc >= 0 && cc < 128) v = vsp[r * 131 + cc];
        w[i] = v;
      }
      float sm = 0.f, s2 = 0.f;
      #pragma unroll
      for (int i = 0; i < 7; ++i) { sm += w[i].x; s2 += w[i].y; }
      float nrmv[8], xv[8];
      #pragma unroll
      for (int o = 0; o < 8; ++o) {
        float mean = sm * (1.f / 49.f);
        float var  = (s2 - sm * mean) * (1.f / 48.f);   // (s2 - s^2/49)/48
        var = var > 0.f ? var : 0.f;
        float sd = __builtin_amdgcn_sqrtf(var);
        float x  = xs[(r + 3) * 129 + c0 + o];
        float nrm = (x - mean) * __builtin_amdgcn_rcpf(sd + 1e-8f);
        if (phase == 0) { meanR[o] = mean; sdR[o] = sd; }
        nrmv[o] = nrm; xv[o] = x;
        if (o < 7) { sm += w[o + 7].x - w[o].x; s2 += w[o + 7].y - w[o].y; }
      }
      #pragma unroll
      for (int op = 0; op < 4; ++op) {
        unsigned int lo32 = pack_bf2(nrmv[2 * op], nrmv[2 * op + 1]);
        float h0, h1;
        if (phase == 0) { h0 = xv[2 * op]; h1 = xv[2 * op + 1]; }
        else {
          h0 = nrmv[2 * op]     * sdR[2 * op]     + meanR[2 * op];
          h1 = nrmv[2 * op + 1] * sdR[2 * op + 1] + meanR[2 * op + 1];
        }
        unsigned int hi32 = pack_bf2(h0, h1);
        int m = (c0 >> 1) + op;                  // u32-pair column 0..63
        obI[r * 64 + ((m + r) & 63)] = ((unsigned long long)hi32 << 32) | lo32;
      }
    }
    __syncthreads();
    {
      int r  = t >> 4;
      int mg = (t & 15) * 4;
      unsigned int t0[4], t1[4];
      #pragma unroll
      for (int k2 = 0; k2 < 4; ++k2) {
        unsigned long long v = obI[r * 64 + ((mg + k2 + r) & 63)];
        t0[k2] = (unsigned int)v;
        t1[k2] = (unsigned int)(v >> 32);
      }
      size_t gb = planeOff + (size_t)(r0 + r) * 128 + (size_t)mg * 2;
      int tn0 = (phase == 0) ? 1 : 0;
      int tn1 = (phase == 0) ? 3 : 2;
      *(uint4v*)(xcm + (size_t)tn0 * TSZ + gb) = (uint4v){t0[0], t0[1], t0[2], t0[3]};
      *(uint4v*)(xcm + (size_t)tn1 * TSZ + gb) = (uint4v){t1[0], t1[1], t1[2], t1[3]};
    }
  }
}

// ---------------------------------------------------------------------------
// Kernel 2: four fused conv1x1 GEMMs per 64-pixel tile via bf16 MFMA.
// NEW: B-operand (X) staged in LDS, double-buffered, via global_load_lds(16B)
// with subtile-permuted per-lane global source (LDS dest stays linear).
// LDS layout per 32k x 64px tile: [kb=K/4][pb=P/16][4][16] bf16 subtiles
// (128B each) -> fragments read with ds_read_b64_tr_b16 (HW 4x16 transpose):
// group q reads subtile (kb=2q+h, pb=in); per-lane addr = q*1024 + col*8;
// (h,in) walked by compile-time offset: (h*4+in)*128. Two tr-reads = short8.
// Replaces 8 stride-32KB u16 scalar loads + packing per fragment, and shares
// the staged tile across all 4 waves (4x less global B traffic).
// ---------------------------------------------------------------------------
__device__ __forceinline__ void stage_tile(const unsigned short* __restrict__ X,
                                           int k0, int p0, int t,
                                           unsigned short* dst) {
  // inverse of the subtile layout: LDS 16B-chunk t holds
  //   k = (t>>5)*4 + ((t&7)>>1),  px = ((t>>3)&3)*16 + (t&1)*8
  int kk = ((t >> 5) << 2) + ((t & 7) >> 1);
  int px = (((t >> 3) & 3) << 4) + ((t & 1) << 3);
  const unsigned short* src = X + (size_t)(k0 + kk) * PIX + (size_t)(p0 + px);
  typedef const __attribute__((address_space(1))) unsigned int GUI;
  typedef __attribute__((address_space(3))) unsigned int LUI;
  __builtin_amdgcn_global_load_lds((GUI*)(unsigned long long)src,
                                   (LUI*)(unsigned)(unsigned long long)(dst + t * 8),
                                   16, 0, 0);
}

__device__ __forceinline__ void gemm_tile_lds(const unsigned short* __restrict__ X,
                                              const unsigned short* __restrict__ Wm,
                                              unsigned short* xt, unsigned xbase,
                                              int mbase, int lane, int p0, int t,
                                              float4v acc[4][4]) {
  int col = lane & 15;
  int q   = lane >> 4;
  unsigned tra = xbase + (unsigned)((q << 10) + (col << 3));

  #pragma unroll
  for (int in = 0; in < 4; ++in)
    #pragma unroll
    for (int im = 0; im < 4; ++im)
      acc[in][im] = (float4v){0.f, 0.f, 0.f, 0.f};

  stage_tile(X, 0, p0, t, xt);         // prologue: fill buf0
  __syncthreads();                      // drains vmcnt(0): buf0 ready

  #pragma unroll
  for (int i = 0; i < 8; ++i) {
    int kq = i * 32 + q * 8;
    // A fragments (weights, L2-hot) -- issued BEFORE the stage so the
    // compiler's wait for af is vmcnt(1), leaving the stage in flight.
    short8 af[4];
    #pragma unroll
    for (int im = 0; im < 4; ++im)
      af[im] = *(const short8*)(Wm + (mbase + im * 16 + col) * 256 + kq);
    if (i < 7) stage_tile(X, i * 32 + 32, p0, t, xt + (((i & 1) ^ 1) << 11));

    unsigned a = tra + (unsigned)((i & 1) << 12);
    uint2v r0, r1, r2, r3, r4, r5, r6, r7;
    asm volatile("ds_read_b64_tr_b16 %0, %1 offset:0"   : "=v"(r0) : "v"(a));
    asm volatile("ds_read_b64_tr_b16 %0, %1 offset:512" : "=v"(r1) : "v"(a));
    asm volatile("ds_read_b64_tr_b16 %0, %1 offset:128" : "=v"(r2) : "v"(a));
    asm volatile("ds_read_b64_tr_b16 %0, %1 offset:640" : "=v"(r3) : "v"(a));
    asm volatile("ds_read_b64_tr_b16 %0, %1 offset:256" : "=v"(r4) : "v"(a));
    asm volatile("ds_read_b64_tr_b16 %0, %1 offset:768" : "=v"(r5) : "v"(a));
    asm volatile("ds_read_b64_tr_b16 %0, %1 offset:384" : "=v"(r6) : "v"(a));
    asm volatile("ds_read_b64_tr_b16 %0, %1 offset:896" : "=v"(r7) : "v"(a));
    asm volatile("s_waitcnt lgkmcnt(0)" ::: "memory");
    __builtin_amdgcn_sched_barrier(0);   // rule #18: keep MFMA below the wait

    union BU { unsigned u[4]; short8 s; };
    BU b0, b1, b2, b3;
    b0.u[0] = r0[0]; b0.u[1] = r0[1]; b0.u[2] = r1[0]; b0.u[3] = r1[1];
    b1.u[0] = r2[0]; b1.u[1] = r2[1]; b1.u[2] = r3[0]; b1.u[3] = r3[1];
    b2.u[0] = r4[0]; b2.u[1] = r4[1]; b2.u[2] = r5[0]; b2.u[3] = r5[1];
    b3.u[0] = r6[0]; b3.u[1] = r6[1]; b3.u[2] = r7[0]; b3.u[3] = r7[1];
    short8 bf0 = b0.s, bf1 = b1.s, bf2 = b2.s, bf3 = b3.s;

    #pragma unroll
    for (int im = 0; im < 4; ++im) {
      acc[0][im] = __builtin_amdgcn_mfma_f32_16x16x32_bf16(af[im], bf0, acc[0][im], 0, 0, 0);
      acc[1][im] = __builtin_amdgcn_mfma_f32_16x16x32_bf16(af[im], bf1, acc[1][im], 0, 0, 0);
      acc[2][im] = __builtin_amdgcn_mfma_f32_16x16x32_bf16(af[im], bf2, acc[2][im], 0, 0, 0);
      acc[3][im] = __builtin_amdgcn_mfma_f32_16x16x32_bf16(af[im], bf3, acc[3][im], 0, 0, 0);
    }
    __syncthreads();   // next buffer staged (vmcnt drain) + cur free for re-stage
  }
}

__global__ __launch_bounds__(256, 2) void k_gemm(const unsigned short* __restrict__ xcm,
                                                 const unsigned short* __restrict__ wbf,
                                                 const float* __restrict__ bFF,
                                                 const float* __restrict__ bGG,
                                                 const float* __restrict__ bEE,
                                                 const float* __restrict__ bHH,
                                                 unsigned short* __restrict__ eecm,
                                                 unsigned short* __restrict__ hhcm,
                                                 float* __restrict__ Sout) {
  int blk  = blockIdx.x;
  int b    = blk >> 8;
  int p0   = (blk & 255) * 64;
  int t    = threadIdx.x;
  int wv   = t >> 6;
  int lane = t & 63;
  int col  = lane & 15;
  int q    = lane >> 4;
  int mbase = wv * 64;

  __shared__ __align__(16) unsigned short xt[2][2048];   // 8 KB dbuf X tile
  __shared__ float sred[3 * 64];       // dot, |F|^2, |G|^2 per pixel
  if (t < 192) sred[t] = 0.f;
  __syncthreads();
  unsigned xbase = (unsigned)(unsigned long long)&xt[0][0];

  const unsigned short* Xb = xcm + (size_t)b * (256 * PIX);

  float4v aF[4][4], aG[4][4];

  // FF = wf * front_norm + bf ; GG = wg * back_norm + bg
  gemm_tile_lds(Xb + 0 * TSZ, wbf + 0 * 65536, &xt[0][0], xbase, mbase, lane, p0, t, aF);
  gemm_tile_lds(Xb + 1 * TSZ, wbf + 1 * 65536, &xt[0][0], xbase, mbase, lane, p0, t, aG);
  #pragma unroll
  for (int im = 0; im < 4; ++im) {
    float4v bvF = *(const float4v*)(bFF + mbase + im * 16 + q * 4);
    float4v bvG = *(const float4v*)(bGG + mbase + im * 16 + q * 4);
    #pragma unroll
    for (int in = 0; in < 4; ++in) { aF[in][im] += bvF; aG[in][im] += bvG; }
  }
  // cosine partials: lane-local over 16 m's, then quad shuffle, then LDS
  #pragma unroll
  for (int in = 0; in < 4; ++in) {
    float d = 0.f, nf = 0.f, ng = 0.f;
    #pragma unroll
    for (int im = 0; im < 4; ++im)
      #pragma unroll
      for (int r = 0; r < 4; ++r) {
        float f = aF[in][im][r], g = aG[in][im][r];
        d += f * g; nf += f * f; ng += g * g;
      }
    d  += __shfl_xor(d, 16);  d  += __shfl_xor(d, 32);
    nf += __shfl_xor(nf, 16); nf += __shfl_xor(nf, 32);
    ng += __shfl_xor(ng, 16); ng += __shfl_xor(ng, 32);
    if (lane < 16) {
      atomicAdd(&sred[0 * 64 + in * 16 + lane], d);
      atomicAdd(&sred[1 * 64 + in * 16 + lane], nf);
      atomicAdd(&sred[2 * 64 + in * 16 + lane], ng);
    }
  }
  // EE = we * adain + be  -> store bf16 channel-major
  gemm_tile_lds(Xb + 2 * TSZ, wbf + 2 * 65536, &xt[0][0], xbase, mbase, lane, p0, t, aF);
  #pragma unroll
  for (int im = 0; im < 4; ++im) {
    float4v bv = *(const float4v*)(bEE + mbase + im * 16 + q * 4);
    #pragma unroll
    for (int in = 0; in < 4; ++in)
      #pragma unroll
      for (int r = 0; r < 4; ++r) {
        int m = mbase + im * 16 + q * 4 + r;
        eecm[((size_t)(b * 256 + m)) * PIX + p0 + in * 16 + col] = f2bf(aF[in][im][r] + bv[r]);
      }
  }
  // HH = wh * back + bh
  gemm_tile_lds(Xb + 3 * TSZ, wbf + 3 * 65536, &xt[0][0], xbase, mbase, lane, p0, t, aG);
  #pragma unroll
  for (int im = 0; im < 4; ++im) {
    float4v bv = *(const float4v*)(bHH + mbase + im * 16 + q * 4);
    #pragma unroll
    for (int in = 0; in < 4; ++in)
      #pragma unroll
      for (int r = 0; r < 4; ++r) {
        int m = mbase + im * 16 + q * 4 + r;
        hhcm[((size_t)(b * 256 + m)) * PIX + p0 + in * 16 + col] = f2bf(aG[in][im][r] + bv[r]);
      }
  }
  __syncthreads();
  if (t < 64) {
    float d = sred[t], nf = sred[64 + t], ng = sred[128 + t];
    Sout[(size_t)b * PIX + p0 + t] = d / (sqrtf(nf) * sqrtf(ng));
  }
}

// ---------------------------------------------------------------------------
// Kernel 3: per-batch min/max of S (one block per batch)
// ---------------------------------------------------------------------------
__global__ __launch_bounds__(256) void k_minmax(const float* __restrict__ S,
                                                float* __restrict__ mm) {
  int b = blockIdx.x, t = threadIdx.x;
  const float* sp = S + (size_t)b * PIX;
  float mn = 3.0e38f, mx = -3.0e38f;
  for (int i = t; i < PIX; i += 256) { float v = sp[i]; mn = fminf(mn, v); mx = fmaxf(mx, v); }
  #pragma unroll
  for (int o = 32; o >= 1; o >>= 1) {
    mn = fminf(mn, __shfl_xor(mn, o));
    mx = fmaxf(mx, __shfl_xor(mx, o));
  }
  __shared__ float smn[4], smx[4];
  if ((t & 63) == 0) { smn[t >> 6] = mn; smx[t >> 6] = mx; }
  __syncthreads();
  if (t == 0) {
    mn = fminf(fminf(smn[0], smn[1]), fminf(smn[2], smn[3]));
    mx = fmaxf(fmaxf(smx[0], smx[1]), fmaxf(smx[2], smx[3]));
    mm[b * 2] = mn; mm[b * 2 + 1] = mx;
  }
}

// ---------------------------------------------------------------------------
// Kernel 4: fused = S_n*EE + (1-S_n)*HH  (fp32 out, fully coalesced)
// ---------------------------------------------------------------------------
__global__ __launch_bounds__(256) void k_blend(const unsigned short* __restrict__ ee,
                                               const unsigned short* __restrict__ hh,
                                               const float* __restrict__ S,
                                               const float* __restrict__ mm,
                                               float* __restrict__ out) {
  size_t base = ((size_t)blockIdx.x * 256 + threadIdx.x) * 8;
  int b = (int)(base >> 22);            // / (256*16384)
  int p = (int)(base & 16383);
  float mn = mm[b * 2], mx = mm[b * 2 + 1];
  float inv = 1.f / (mx - mn);
  uint4v eu = *(const uint4v*)(ee + base);
  uint4v hu = *(const uint4v*)(hh + base);
  const float* sp = S + ((size_t)b << 14) + p;
  float4v s0 = *(const float4v*)(sp);
  float4v s1 = *(const float4v*)(sp + 4);
  float sv[8];
  #pragma unroll
  for (int i = 0; i < 4; ++i) { sv[i] = s0[i]; sv[4 + i] = s1[i]; }
  float ov[8];
  #pragma unroll
  for (int i = 0; i < 4; ++i) {
    unsigned int ew = eu[i], hw = hu[i];
    float e0 = bf2f((unsigned short)(ew & 0xffffu));
    float e1 = bf2f((unsigned short)(ew >> 16));
    float h0 = bf2f((unsigned short)(hw & 0xffffu));
    float h1 = bf2f((unsigned short)(hw >> 16));
    float a0 = (sv[2 * i] - mn) * inv;
    float a1 = (sv[2 * i + 1] - mn) * inv;
    ov[2 * i]     = h0 + a0 * (e0 - h0);
    ov[2 * i + 1] = h1 + a1 * (e1 - h1);
  }
  float4v r0 = {ov[0], ov[1], ov[2], ov[3]};
  float4v r1 = {ov[4], ov[5], ov[6], ov[7]};
  *(float4v*)(out + base)     = r0;
  *(float4v*)(out + base + 4) = r1;
}

// ---------------------------------------------------------------------------
// Workspace layout (bytes):
//   0          : xcm   4 tensors bf16, 4*TSZ*2   = 268,435,456
//   268435456  : wbf   4x256x256 bf16            =     524,288
//   268959744  : eecm  bf16                      =  67,108,864
//   336068608  : hhcm  bf16                      =  67,108,864
//   403177472  : S     fp32 8x16384              =     524,288
//   403701760  : mm    fp32 8x2                  =          64
// total ~403.7 MB
// ---------------------------------------------------------------------------
extern "C" void kernel_launch(void* const* d_in, const int* in_sizes, int n_in,
                              void* d_out, int out_size, void* d_ws, size_t ws_size,
                              hipStream_t stream) {
  const float* front = (const float*)d_in[0];
  const float* back  = (const float*)d_in[1];
  // d_in[2] = mask (unused by reference)
  const float* we = (const float*)d_in[3];
  const float* be = (const float*)d_in[4];
  const float* wf = (const float*)d_in[5];
  const float* bf = (const float*)d_in[6];
  const float* wg = (const float*)d_in[7];
  const float* bg = (const float*)d_in[8];
  const float* wh = (const float*)d_in[9];
  const float* bh = (const float*)d_in[10];

  char* ws = (char*)d_ws;
  unsigned short* xcm  = (unsigned short*)(ws);
  unsigned short* wbf  = (unsigned short*)(ws + 268435456);
  unsigned short* eecm = (unsigned short*)(ws + 268959744);
  unsigned short* hhcm = (unsigned short*)(ws + 336068608);
  float*          S    = (float*)(ws + 403177472);
  float*          mm   = (float*)(ws + 403701760);
  float*          out  = (float*)d_out;

  k_prep  <<<1024,  256, 0, stream>>>(we, wf, wg, wh, wbf);
  k_stats <<<16384, 256, 0, stream>>>(front, back, xcm);
  k_gemm  <<<2048,  256, 0, stream>>>(xcm, wbf, bf, bg, be, bh, eecm, hhcm, S);
  k_minmax<<<8,     256, 0, stream>>>(S, mm);
  k_blend <<<16384, 256, 0, stream>>>(eecm, hhcm, S, mm, out);
}

// Round 2
// 660.519 us; speedup vs baseline: 1.0757x; 1.0031x over previous
//
#include <hip/hip_runtime.h>
#include <math.h>

// Problem constants: B=8, C=256, H=W=128
#define PIX 16384                       // H*W
#define TSZ ((size_t)33554432)          // 8*256*16384 elements per tensor

typedef __attribute__((ext_vector_type(8))) short  short8;   // 8 x bf16 (4 VGPRs)
typedef __attribute__((ext_vector_type(4))) float  float4v;
typedef __attribute__((ext_vector_type(4))) unsigned int uint4v;
typedef __attribute__((ext_vector_type(2))) unsigned int uint2v;

__device__ __forceinline__ unsigned short f2bf(float x) {
  unsigned int u = __float_as_uint(x);
  u += 0x7fffu + ((u >> 16) & 1u);      // round-to-nearest-even
  return (unsigned short)(u >> 16);
}
__device__ __forceinline__ float bf2f(unsigned short h) {
  return __uint_as_float(((unsigned int)h) << 16);
}
// pack two fp32 -> (bf16(hi)<<16)|bf16(lo) via v_perm_b32
__device__ __forceinline__ unsigned int pack_bf2(float lo, float hi) {
  unsigned int ul = __float_as_uint(lo); ul += 0x7fffu + ((ul >> 16) & 1u);
  unsigned int uh = __float_as_uint(hi); uh += 0x7fffu + ((uh >> 16) & 1u);
  return __builtin_amdgcn_perm(uh, ul, 0x07060302u);  // [ul.b2,ul.b3,uh.b2,uh.b3]
}

// ---------------------------------------------------------------------------
// Kernel 0: convert the four 256x256 weight matrices to bf16.
// Conv order: 0=FF(wf), 1=GG(wg), 2=EE(we), 3=HH(wh)
// ---------------------------------------------------------------------------
__global__ __launch_bounds__(256) void k_prep(const float* __restrict__ we,
                                              const float* __restrict__ wf,
                                              const float* __restrict__ wg,
                                              const float* __restrict__ wh,
                                              unsigned short* __restrict__ wbf) {
  int idx = blockIdx.x * 256 + threadIdx.x;      // 0 .. 262143
  int which = idx >> 16, off = idx & 65535;
  const float* src = (which == 0) ? wf : (which == 1) ? wg : (which == 2) ? we : wh;
  wbf[idx] = f2bf(src[off]);
}

// ---------------------------------------------------------------------------
// Kernel 1: 7x7 patch stats (zero-padded box sums), normalization, adain.
// (unchanged this round)
// ---------------------------------------------------------------------------
__global__ __launch_bounds__(256, 4) void k_stats(const float* __restrict__ front,
                                                  const float* __restrict__ back,
                                                  unsigned short* __restrict__ xcm) {
  int blk = blockIdx.x;
  int s   = blk & 7;            // strip (16 rows)
  int c   = (blk >> 3) & 255;
  int b   = blk >> 11;
  int t   = threadIdx.x;
  int r0  = s * 16;

  __shared__ float  xs[22 * 129];
  __shared__ float2 vsp[16 * 131];
  __shared__ unsigned long long obI[16 * 64];

  size_t planeOff = ((size_t)(b * 256 + c)) * PIX;

  float meanR[8], sdR[8];       // back stats, phase0 -> phase1 carry

  #pragma unroll 1
  for (int phase = 0; phase < 2; ++phase) {     // 0 = back, 1 = front
    const float* src = (phase == 0 ? back : front) + planeOff;
    #pragma unroll
    for (int i = 0; i < 3; ++i) {
      int idx = t + i * 256;                     // 704 = 22*32 float4s
      if (idx < 704) {
        int l = idx >> 5, cv = (idx & 31) * 4;
        int g = r0 - 3 + l;
        float4v v = {0.f, 0.f, 0.f, 0.f};
        if (g >= 0 && g < 128) v = *(const float4v*)(src + g * 128 + cv);
        xs[l * 129 + cv]     = v[0];
        xs[l * 129 + cv + 1] = v[1];
        xs[l * 129 + cv + 2] = v[2];
        xs[l * 129 + cv + 3] = v[3];
      }
    }
    __syncthreads();
    {
      int col = t & 127;
      int rg  = (t >> 7) * 8;                    // 8 output rows per thread
      float sm = 0.f, s2 = 0.f;
      #pragma unroll
      for (int j = 0; j < 7; ++j) { float v = xs[(rg + j) * 129 + col]; sm += v; s2 = fmaf(v, v, s2); }
      vsp[rg * 131 + col] = make_float2(sm, s2);
      #pragma unroll
      for (int o = 1; o < 8; ++o) {
        float vn = xs[(rg + o + 6) * 129 + col];
        float vo = xs[(rg + o - 1) * 129 + col];
        sm += vn - vo;
        s2 += vn * vn - vo * vo;
        vsp[(rg + o) * 131 + col] = make_float2(sm, s2);
      }
    }
    __syncthreads();
    {
      int r  = t & 15;
      int c0 = (t >> 4) * 8;                     // 8 output cols per thread
      float2 w[14];
      #pragma unroll
      for (int i = 0; i < 14; ++i) {
        int cc = c0 - 3 + i;
        float2 v = make_float2(0.f, 0.f);
        if (cc >= 0 && cc < 128) v = vsp[r * 131 + cc];
        w[i] = v;
      }
      float sm = 0.f, s2 = 0.f;
      #pragma unroll
      for (int i = 0; i < 7; ++i) { sm += w[i].x; s2 += w[i].y; }
      float nrmv[8], xv[8];
      #pragma unroll
      for (int o = 0; o < 8; ++o) {
        float mean = sm * (1.f / 49.f);
        float var  = (s2 - sm * mean) * (1.f / 48.f);   // (s2 - s^2/49)/48
        var = var > 0.f ? var : 0.f;
        float sd = __builtin_amdgcn_sqrtf(var);
        float x  = xs[(r + 3) * 129 + c0 + o];
        float nrm = (x - mean) * __builtin_amdgcn_rcpf(sd + 1e-8f);
        if (phase == 0) { meanR[o] = mean; sdR[o] = sd; }
        nrmv[o] = nrm; xv[o] = x;
        if (o < 7) { sm += w[o + 7].x - w[o].x; s2 += w[o + 7].y - w[o].y; }
      }
      #pragma unroll
      for (int op = 0; op < 4; ++op) {
        unsigned int lo32 = pack_bf2(nrmv[2 * op], nrmv[2 * op + 1]);
        float h0, h1;
        if (phase == 0) { h0 = xv[2 * op]; h1 = xv[2 * op + 1]; }
        else {
          h0 = nrmv[2 * op]     * sdR[2 * op]     + meanR[2 * op];
          h1 = nrmv[2 * op + 1] * sdR[2 * op + 1] + meanR[2 * op + 1];
        }
        unsigned int hi32 = pack_bf2(h0, h1);
        int m = (c0 >> 1) + op;                  // u32-pair column 0..63
        obI[r * 64 + ((m + r) & 63)] = ((unsigned long long)hi32 << 32) | lo32;
      }
    }
    __syncthreads();
    {
      int r  = t >> 4;
      int mg = (t & 15) * 4;
      unsigned int t0[4], t1[4];
      #pragma unroll
      for (int k2 = 0; k2 < 4; ++k2) {
        unsigned long long v = obI[r * 64 + ((mg + k2 + r) & 63)];
        t0[k2] = (unsigned int)v;
        t1[k2] = (unsigned int)(v >> 32);
      }
      size_t gb = planeOff + (size_t)(r0 + r) * 128 + (size_t)mg * 2;
      int tn0 = (phase == 0) ? 1 : 0;
      int tn1 = (phase == 0) ? 3 : 2;
      *(uint4v*)(xcm + (size_t)tn0 * TSZ + gb) = (uint4v){t0[0], t0[1], t0[2], t0[3]};
      *(uint4v*)(xcm + (size_t)tn1 * TSZ + gb) = (uint4v){t1[0], t1[1], t1[2], t1[3]};
    }
  }
}

// ---------------------------------------------------------------------------
// Kernel 2: four fused conv1x1 GEMMs per 64-pixel tile via bf16 MFMA.
// R2: T3+T4 counted-vmcnt pipeline. 5 LDS X-buffers (4KB each), stage depth 3
// via global_load_lds(16B); weights prefetched 2 steps ahead into a 3-deep
// register rotation. Per step: [stage(i+3)][A(i+2)][vmcnt(N)][s_barrier]
// [tr-reads buf i][lgkmcnt(0)][16 MFMA]. vmcnt is counted (table below),
// NEVER 0 in steady state; the barrier sits AFTER the vmcnt so that once all
// waves pass it the buffer is globally resident. Slot-reuse safety: stage(i+3)
// targets slot (i+3)%5 == (i-2)%5, whose readers all passed barrier(i-1).
// Issue order pinned with sched_barrier(0) so the vmcnt FIFO counts are exact.
// ---------------------------------------------------------------------------
#define SB0   __builtin_amdgcn_sched_barrier(0)
#define BARR  __builtin_amdgcn_s_barrier()
#define LGKM0 asm volatile("s_waitcnt lgkmcnt(0)" ::: "memory")
#define VMC(n) asm volatile("s_waitcnt vmcnt(" #n ")" ::: "memory")

__device__ __forceinline__ void stage_tile(const unsigned short* __restrict__ X,
                                           int k0, int p0, int t,
                                           unsigned short* dst) {
  // inverse of the subtile layout: LDS 16B-chunk t holds
  //   k = (t>>5)*4 + ((t&7)>>1),  px = ((t>>3)&3)*16 + (t&1)*8
  int kk = ((t >> 5) << 2) + ((t & 7) >> 1);
  int px = (((t >> 3) & 3) << 4) + ((t & 1) << 3);
  const unsigned short* src = X + (size_t)(k0 + kk) * PIX + (size_t)(p0 + px);
  typedef const __attribute__((address_space(1))) unsigned int GUI;
  typedef __attribute__((address_space(3))) unsigned int LUI;
  __builtin_amdgcn_global_load_lds((GUI*)(unsigned long long)src,
                                   (LUI*)(unsigned)(unsigned long long)(dst + t * 8),
                                   16, 0, 0);
}

#define LOADA(S, I) {                                           \
  af[S][0] = *(const short8*)(Wr + 0 * 4096 + (I) * 32);        \
  af[S][1] = *(const short8*)(Wr + 1 * 4096 + (I) * 32);        \
  af[S][2] = *(const short8*)(Wr + 2 * 4096 + (I) * 32);        \
  af[S][3] = *(const short8*)(Wr + 3 * 4096 + (I) * 32); }

#define TR8(O0,O1,O2,O3,O4,O5,O6,O7)                                              \
  asm volatile("ds_read_b64_tr_b16 %0, %1 offset:" #O0 : "=v"(r0) : "v"(tra));    \
  asm volatile("ds_read_b64_tr_b16 %0, %1 offset:" #O1 : "=v"(r1) : "v"(tra));    \
  asm volatile("ds_read_b64_tr_b16 %0, %1 offset:" #O2 : "=v"(r2) : "v"(tra));    \
  asm volatile("ds_read_b64_tr_b16 %0, %1 offset:" #O3 : "=v"(r3) : "v"(tra));    \
  asm volatile("ds_read_b64_tr_b16 %0, %1 offset:" #O4 : "=v"(r4) : "v"(tra));    \
  asm volatile("ds_read_b64_tr_b16 %0, %1 offset:" #O5 : "=v"(r5) : "v"(tra));    \
  asm volatile("ds_read_b64_tr_b16 %0, %1 offset:" #O6 : "=v"(r6) : "v"(tra));    \
  asm volatile("ds_read_b64_tr_b16 %0, %1 offset:" #O7 : "=v"(r7) : "v"(tra));

#define DOMFMA(MS) {                                                        \
  union BU { unsigned u[4]; short8 s; } bu0, bu1, bu2, bu3;                 \
  bu0.u[0]=r0[0]; bu0.u[1]=r0[1]; bu0.u[2]=r1[0]; bu0.u[3]=r1[1];           \
  bu1.u[0]=r2[0]; bu1.u[1]=r2[1]; bu1.u[2]=r3[0]; bu1.u[3]=r3[1];           \
  bu2.u[0]=r4[0]; bu2.u[1]=r4[1]; bu2.u[2]=r5[0]; bu2.u[3]=r5[1];           \
  bu3.u[0]=r6[0]; bu3.u[1]=r6[1]; bu3.u[2]=r7[0]; bu3.u[3]=r7[1];           \
  short8 bv0 = bu0.s, bv1 = bu1.s, bv2 = bu2.s, bv3 = bu3.s;                \
  _Pragma("unroll")                                                         \
  for (int im = 0; im < 4; ++im) {                                          \
    acc[0][im] = __builtin_amdgcn_mfma_f32_16x16x32_bf16(af[MS][im], bv0, acc[0][im], 0, 0, 0); \
    acc[1][im] = __builtin_amdgcn_mfma_f32_16x16x32_bf16(af[MS][im], bv1, acc[1][im], 0, 0, 0); \
    acc[2][im] = __builtin_amdgcn_mfma_f32_16x16x32_bf16(af[MS][im], bv2, acc[2][im], 0, 0, 0); \
    acc[3][im] = __builtin_amdgcn_mfma_f32_16x16x32_bf16(af[MS][im], bv3, acc[3][im], 0, 0, 0); \
  } }

// one K-step: optional stage (depth-3), optional A prefetch (2 ahead),
// counted vmcnt, barrier, tr-reads of buf i, MFMA.
#define GSTEP(VN, DOSTAGE, K0, SLOT, DOA, AS, AI, MS, O0,O1,O2,O3,O4,O5,O6,O7) \
  SB0;                                                                          \
  if (DOSTAGE) stage_tile(X, K0, p0, t, xt + (SLOT) * 2048);                    \
  SB0;                                                                          \
  if (DOA) LOADA(AS, AI);                                                       \
  SB0;                                                                          \
  VMC(VN);                                                                      \
  SB0; BARR; SB0;                                                               \
  TR8(O0,O1,O2,O3,O4,O5,O6,O7);                                                 \
  LGKM0; SB0;                                                                   \
  DOMFMA(MS);

__device__ __forceinline__ void gemm_pipe(const unsigned short* __restrict__ X,
                                          const unsigned short* __restrict__ Wm,
                                          unsigned short* xt, unsigned xbase,
                                          int mbase, int lane, int p0, int t,
                                          float4v acc[4][4]) {
  int col = lane & 15;
  int q   = lane >> 4;
  unsigned tra = xbase + (unsigned)((q << 10) + (col << 3));
  const unsigned short* __restrict__ Wr = Wm + (size_t)((mbase + col) * 256 + q * 8);

  short8 af[3][4];
  uint2v r0, r1, r2, r3, r4, r5, r6, r7;

  #pragma unroll
  for (int in = 0; in < 4; ++in)
    #pragma unroll
    for (int im = 0; im < 4; ++im)
      acc[in][im] = (float4v){0.f, 0.f, 0.f, 0.f};

  // top barrier: all waves done reading slots of the previous gemm
  SB0; BARR; SB0;
  stage_tile(X,  0, p0, t, xt + 0 * 2048);
  stage_tile(X, 32, p0, t, xt + 1 * 2048);
  stage_tile(X, 64, p0, t, xt + 2 * 2048);
  SB0;
  LOADA(0, 0);
  SB0;
  LOADA(1, 1);
  SB0;

  //     VN  st  K0  slot  A  AS AI MS   tr offsets (slot*4096 + subtile)
  GSTEP( 9,  1,  96,  3,   1, 2, 2, 0,      0,  512,  128,  640,  256,  768,  384,  896)
  GSTEP(10,  1, 128,  4,   1, 0, 3, 1,   4096, 4608, 4224, 4736, 4352, 4864, 4480, 4992)
  GSTEP(10,  1, 160,  0,   1, 1, 4, 2,   8192, 8704, 8320, 8832, 8448, 8960, 8576, 9088)
  GSTEP(10,  1, 192,  1,   1, 2, 5, 0,  12288,12800,12416,12928,12544,13056,12672,13184)
  GSTEP(10,  1, 224,  2,   1, 0, 6, 1,  16384,16896,16512,17024,16640,17152,16768,17280)
  GSTEP( 9,  0,   0,  0,   1, 1, 7, 2,      0,  512,  128,  640,  256,  768,  384,  896)
  GSTEP( 4,  0,   0,  0,   0, 0, 0, 0,   4096, 4608, 4224, 4736, 4352, 4864, 4480, 4992)
  GSTEP( 0,  0,   0,  0,   0, 0, 0, 1,   8192, 8704, 8320, 8832, 8448, 8960, 8576, 9088)
}

__global__ __launch_bounds__(256, 2) void k_gemm(const unsigned short* __restrict__ xcm,
                                                 const unsigned short* __restrict__ wbf,
                                                 const float* __restrict__ bFF,
                                                 const float* __restrict__ bGG,
                                                 const float* __restrict__ bEE,
                                                 const float* __restrict__ bHH,
                                                 unsigned short* __restrict__ eecm,
                                                 unsigned short* __restrict__ hhcm,
                                                 float* __restrict__ Sout) {
  int blk  = blockIdx.x;
  int b    = blk >> 8;
  int p0   = (blk & 255) * 64;
  int t    = threadIdx.x;
  int wv   = t >> 6;
  int lane = t & 63;
  int col  = lane & 15;
  int q    = lane >> 4;
  int mbase = wv * 64;

  __shared__ __align__(16) unsigned short xt[5][2048];   // 20 KB: 5 X buffers
  __shared__ float sred[3 * 64];       // dot, |F|^2, |G|^2 per pixel
  if (t < 192) sred[t] = 0.f;
  __syncthreads();
  unsigned xbase = (unsigned)(unsigned long long)&xt[0][0];

  const unsigned short* Xb = xcm + (size_t)b * (256 * PIX);

  float4v aF[4][4], aG[4][4];

  // FF = wf * front_norm + bf ; GG = wg * back_norm + bg
  gemm_pipe(Xb + 0 * TSZ, wbf + 0 * 65536, &xt[0][0], xbase, mbase, lane, p0, t, aF);
  gemm_pipe(Xb + 1 * TSZ, wbf + 1 * 65536, &xt[0][0], xbase, mbase, lane, p0, t, aG);
  #pragma unroll
  for (int im = 0; im < 4; ++im) {
    float4v bvF = *(const float4v*)(bFF + mbase + im * 16 + q * 4);
    float4v bvG = *(const float4v*)(bGG + mbase + im * 16 + q * 4);
    #pragma unroll
    for (int in = 0; in < 4; ++in) { aF[in][im] += bvF; aG[in][im] += bvG; }
  }
  // cosine partials: lane-local over 16 m's, then quad shuffle, then LDS
  #pragma unroll
  for (int in = 0; in < 4; ++in) {
    float d = 0.f, nf = 0.f, ng = 0.f;
    #pragma unroll
    for (int im = 0; im < 4; ++im)
      #pragma unroll
      for (int r = 0; r < 4; ++r) {
        float f = aF[in][im][r], g = aG[in][im][r];
        d += f * g; nf += f * f; ng += g * g;
      }
    d  += __shfl_xor(d, 16);  d  += __shfl_xor(d, 32);
    nf += __shfl_xor(nf, 16); nf += __shfl_xor(nf, 32);
    ng += __shfl_xor(ng, 16); ng += __shfl_xor(ng, 32);
    if (lane < 16) {
      atomicAdd(&sred[0 * 64 + in * 16 + lane], d);
      atomicAdd(&sred[1 * 64 + in * 16 + lane], nf);
      atomicAdd(&sred[2 * 64 + in * 16 + lane], ng);
    }
  }
  // EE = we * adain + be  -> store bf16 channel-major
  gemm_pipe(Xb + 2 * TSZ, wbf + 2 * 65536, &xt[0][0], xbase, mbase, lane, p0, t, aF);
  #pragma unroll
  for (int im = 0; im < 4; ++im) {
    float4v bv = *(const float4v*)(bEE + mbase + im * 16 + q * 4);
    #pragma unroll
    for (int in = 0; in < 4; ++in)
      #pragma unroll
      for (int r = 0; r < 4; ++r) {
        int m = mbase + im * 16 + q * 4 + r;
        eecm[((size_t)(b * 256 + m)) * PIX + p0 + in * 16 + col] = f2bf(aF[in][im][r] + bv[r]);
      }
  }
  // HH = wh * back + bh
  gemm_pipe(Xb + 3 * TSZ, wbf + 3 * 65536, &xt[0][0], xbase, mbase, lane, p0, t, aG);
  #pragma unroll
  for (int im = 0; im < 4; ++im) {
    float4v bv = *(const float4v*)(bHH + mbase + im * 16 + q * 4);
    #pragma unroll
    for (int in = 0; in < 4; ++in)
      #pragma unroll
      for (int r = 0; r < 4; ++r) {
        int m = mbase + im * 16 + q * 4 + r;
        hhcm[((size_t)(b * 256 + m)) * PIX + p0 + in * 16 + col] = f2bf(aG[in][im][r] + bv[r]);
      }
  }
  __syncthreads();
  if (t < 64) {
    float d = sred[t], nf = sred[64 + t], ng = sred[128 + t];
    Sout[(size_t)b * PIX + p0 + t] = d / (sqrtf(nf) * sqrtf(ng));
  }
}

// ---------------------------------------------------------------------------
// Kernel 3: per-batch min/max of S (one block per batch)
// ---------------------------------------------------------------------------
__global__ __launch_bounds__(256) void k_minmax(const float* __restrict__ S,
                                                float* __restrict__ mm) {
  int b = blockIdx.x, t = threadIdx.x;
  const float* sp = S + (size_t)b * PIX;
  float mn = 3.0e38f, mx = -3.0e38f;
  for (int i = t; i < PIX; i += 256) { float v = sp[i]; mn = fminf(mn, v); mx = fmaxf(mx, v); }
  #pragma unroll
  for (int o = 32; o >= 1; o >>= 1) {
    mn = fminf(mn, __shfl_xor(mn, o));
    mx = fmaxf(mx, __shfl_xor(mx, o));
  }
  __shared__ float smn[4], smx[4];
  if ((t & 63) == 0) { smn[t >> 6] = mn; smx[t >> 6] = mx; }
  __syncthreads();
  if (t == 0) {
    mn = fminf(fminf(smn[0], smn[1]), fminf(smn[2], smn[3]));
    mx = fmaxf(fmaxf(smx[0], smx[1]), fmaxf(smx[2], smx[3]));
    mm[b * 2] = mn; mm[b * 2 + 1] = mx;
  }
}

// ---------------------------------------------------------------------------
// Kernel 4: fused = S_n*EE + (1-S_n)*HH  (fp32 out, fully coalesced)
// ---------------------------------------------------------------------------
__global__ __launch_bounds__(256) void k_blend(const unsigned short* __restrict__ ee,
                                               const unsigned short* __restrict__ hh,
                                               const float* __restrict__ S,
                                               const float* __restrict__ mm,
                                               float* __restrict__ out) {
  size_t base = ((size_t)blockIdx.x * 256 + threadIdx.x) * 8;
  int b = (int)(base >> 22);            // / (256*16384)
  int p = (int)(base & 16383);
  float mn = mm[b * 2], mx = mm[b * 2 + 1];
  float inv = 1.f / (mx - mn);
  uint4v eu = *(const uint4v*)(ee + base);
  uint4v hu = *(const uint4v*)(hh + base);
  const float* sp = S + ((size_t)b << 14) + p;
  float4v s0 = *(const float4v*)(sp);
  float4v s1 = *(const float4v*)(sp + 4);
  float sv[8];
  #pragma unroll
  for (int i = 0; i < 4; ++i) { sv[i] = s0[i]; sv[4 + i] = s1[i]; }
  float ov[8];
  #pragma unroll
  for (int i = 0; i < 4; ++i) {
    unsigned int ew = eu[i], hw = hu[i];
    float e0 = bf2f((unsigned short)(ew & 0xffffu));
    float e1 = bf2f((unsigned short)(ew >> 16));
    float h0 = bf2f((unsigned short)(hw & 0xffffu));
    float h1 = bf2f((unsigned short)(hw >> 16));
    float a0 = (sv[2 * i] - mn) * inv;
    float a1 = (sv[2 * i + 1] - mn) * inv;
    ov[2 * i]     = h0 + a0 * (e0 - h0);
    ov[2 * i + 1] = h1 + a1 * (e1 - h1);
  }
  float4v r0 = {ov[0], ov[1], ov[2], ov[3]};
  float4v r1 = {ov[4], ov[5], ov[6], ov[7]};
  *(float4v*)(out + base)     = r0;
  *(float4v*)(out + base + 4) = r1;
}

// ---------------------------------------------------------------------------
// Workspace layout (bytes):
//   0          : xcm   4 tensors bf16, 4*TSZ*2   = 268,435,456
//   268435456  : wbf   4x256x256 bf16            =     524,288
//   268959744  : eecm  bf16                      =  67,108,864
//   336068608  : hhcm  bf16                      =  67,108,864
//   403177472  : S     fp32 8x16384              =     524,288
//   403701760  : mm    fp32 8x2                  =          64
// total ~403.7 MB
// ---------------------------------------------------------------------------
extern "C" void kernel_launch(void* const* d_in, const int* in_sizes, int n_in,
                              void* d_out, int out_size, void* d_ws, size_t ws_size,
                              hipStream_t stream) {
  const float* front = (const float*)d_in[0];
  const float* back  = (const float*)d_in[1];
  // d_in[2] = mask (unused by reference)
  const float* we = (const float*)d_in[3];
  const float* be = (const float*)d_in[4];
  const float* wf = (const float*)d_in[5];
  const float* bf = (const float*)d_in[6];
  const float* wg = (const float*)d_in[7];
  const float* bg = (const float*)d_in[8];
  const float* wh = (const float*)d_in[9];
  const float* bh = (const float*)d_in[10];

  char* ws = (char*)d_ws;
  unsigned short* xcm  = (unsigned short*)(ws);
  unsigned short* wbf  = (unsigned short*)(ws + 268435456);
  unsigned short* eecm = (unsigned short*)(ws + 268959744);
  unsigned short* hhcm = (unsigned short*)(ws + 336068608);
  float*          S    = (float*)(ws + 403177472);
  float*          mm   = (float*)(ws + 403701760);
  float*          out  = (float*)d_out;

  k_prep  <<<1024,  256, 0, stream>>>(we, wf, wg, wh, wbf);
  k_stats <<<16384, 256, 0, stream>>>(front, back, xcm);
  k_gemm  <<<2048,  256, 0, stream>>>(xcm, wbf, bf, bg, be, bh, eecm, hhcm, S);
  k_minmax<<<8,     256, 0, stream>>>(S, mm);
  k_blend <<<16384, 256, 0, stream>>>(eecm, hhcm, S, mm, out);
}

// Round 3
// 593.276 us; speedup vs baseline: 1.1976x; 1.1133x over previous
//
#include <hip/hip_runtime.h>
#include <math.h>

// Problem constants: B=8, C=256, H=W=128
#define PIX 16384                       // H*W
#define TSZ ((size_t)33554432)          // 8*256*16384 elements per tensor

typedef __attribute__((ext_vector_type(8))) short  short8;   // 8 x bf16 (4 VGPRs)
typedef __attribute__((ext_vector_type(4))) float  float4v;
typedef __attribute__((ext_vector_type(4))) unsigned int uint4v;
typedef __attribute__((ext_vector_type(2))) unsigned int uint2v;

__device__ __forceinline__ unsigned short f2bf(float x) {
  unsigned int u = __float_as_uint(x);
  u += 0x7fffu + ((u >> 16) & 1u);      // round-to-nearest-even
  return (unsigned short)(u >> 16);
}
__device__ __forceinline__ float bf2f(unsigned short h) {
  return __uint_as_float(((unsigned int)h) << 16);
}
// pack two fp32 -> (bf16(hi)<<16)|bf16(lo) via v_perm_b32
__device__ __forceinline__ unsigned int pack_bf2(float lo, float hi) {
  unsigned int ul = __float_as_uint(lo); ul += 0x7fffu + ((ul >> 16) & 1u);
  unsigned int uh = __float_as_uint(hi); uh += 0x7fffu + ((uh >> 16) & 1u);
  return __builtin_amdgcn_perm(uh, ul, 0x07060302u);  // [ul.b2,ul.b3,uh.b2,uh.b3]
}

// ---------------------------------------------------------------------------
// Kernel 0: weights -> bf16, PACKED for lane-linear 1KB wave loads.
// Layout (shorts): wpk[g][i=kstep(8)][wv(4)][im(4)][lane(64)][e(8)]
//   lane=(q<<4)|col;  m = wv*64+im*16+col;  k = i*32+q*8+e
// Every gemm A-load becomes one contiguous 16B/lane load (ideal coalescing).
// ---------------------------------------------------------------------------
__global__ __launch_bounds__(256) void k_prep(const float* __restrict__ we,
                                              const float* __restrict__ wf,
                                              const float* __restrict__ wg,
                                              const float* __restrict__ wh,
                                              unsigned short* __restrict__ wbf) {
  int idx = blockIdx.x * 256 + threadIdx.x;      // 0 .. 262143
  int g = idx >> 16, within = idx & 65535;
  const float* src = (g == 0) ? wf : (g == 1) ? wg : (g == 2) ? we : wh;
  int e    = within & 7;
  int lane = (within >> 3) & 63;
  int im   = (within >> 9) & 3;
  int wv   = (within >> 11) & 3;
  int i    = within >> 13;
  int col = lane & 15, q = lane >> 4;
  int m = wv * 64 + im * 16 + col;
  int k = i * 32 + q * 8 + e;
  wbf[idx] = f2bf(src[m * 256 + k]);
}

// ---------------------------------------------------------------------------
// Kernel 1: 7x7 patch stats (zero-padded box sums), normalization, adain.
// Output now TILED: xcm[tens][b][pt(256)][k=c(256)][px(64)] bf16, so that
// k_gemm's 32k x 64px stage buffer is one CONTIGUOUS 4KB region.
// ---------------------------------------------------------------------------
__global__ __launch_bounds__(256, 4) void k_stats(const float* __restrict__ front,
                                                  const float* __restrict__ back,
                                                  unsigned short* __restrict__ xcm) {
  int blk = blockIdx.x;
  int s   = blk & 7;            // strip (16 rows)
  int c   = (blk >> 3) & 255;
  int b   = blk >> 11;
  int t   = threadIdx.x;
  int r0  = s * 16;

  __shared__ float  xs[22 * 129];
  __shared__ float2 vsp[16 * 131];
  __shared__ unsigned long long obI[16 * 64];

  size_t planeOff = ((size_t)(b * 256 + c)) * PIX;

  float meanR[8], sdR[8];       // back stats, phase0 -> phase1 carry

  #pragma unroll 1
  for (int phase = 0; phase < 2; ++phase) {     // 0 = back, 1 = front
    const float* src = (phase == 0 ? back : front) + planeOff;
    #pragma unroll
    for (int i = 0; i < 3; ++i) {
      int idx = t + i * 256;                     // 704 = 22*32 float4s
      if (idx < 704) {
        int l = idx >> 5, cv = (idx & 31) * 4;
        int g = r0 - 3 + l;
        float4v v = {0.f, 0.f, 0.f, 0.f};
        if (g >= 0 && g < 128) v = *(const float4v*)(src + g * 128 + cv);
        xs[l * 129 + cv]     = v[0];
        xs[l * 129 + cv + 1] = v[1];
        xs[l * 129 + cv + 2] = v[2];
        xs[l * 129 + cv + 3] = v[3];
      }
    }
    __syncthreads();
    {
      int col = t & 127;
      int rg  = (t >> 7) * 8;                    // 8 output rows per thread
      float sm = 0.f, s2 = 0.f;
      #pragma unroll
      for (int j = 0; j < 7; ++j) { float v = xs[(rg + j) * 129 + col]; sm += v; s2 = fmaf(v, v, s2); }
      vsp[rg * 131 + col] = make_float2(sm, s2);
      #pragma unroll
      for (int o = 1; o < 8; ++o) {
        float vn = xs[(rg + o + 6) * 129 + col];
        float vo = xs[(rg + o - 1) * 129 + col];
        sm += vn - vo;
        s2 += vn * vn - vo * vo;
        vsp[(rg + o) * 131 + col] = make_float2(sm, s2);
      }
    }
    __syncthreads();
    {
      int r  = t & 15;
      int c0 = (t >> 4) * 8;                     // 8 output cols per thread
      float2 w[14];
      #pragma unroll
      for (int i = 0; i < 14; ++i) {
        int cc = c0 - 3 + i;
        float2 v = make_float2(0.f, 0.f);
        if (cc >= 0 && cc < 128) v = vsp[r * 131 + cc];
        w[i] = v;
      }
      float sm = 0.f, s2 = 0.f;
      #pragma unroll
      for (int i = 0; i < 7; ++i) { sm += w[i].x; s2 += w[i].y; }
      float nrmv[8], xv[8];
      #pragma unroll
      for (int o = 0; o < 8; ++o) {
        float mean = sm * (1.f / 49.f);
        float var  = (s2 - sm * mean) * (1.f / 48.f);   // (s2 - s^2/49)/48
        var = var > 0.f ? var : 0.f;
        float sd = __builtin_amdgcn_sqrtf(var);
        float x  = xs[(r + 3) * 129 + c0 + o];
        float nrm = (x - mean) * __builtin_amdgcn_rcpf(sd + 1e-8f);
        if (phase == 0) { meanR[o] = mean; sdR[o] = sd; }
        nrmv[o] = nrm; xv[o] = x;
        if (o < 7) { sm += w[o + 7].x - w[o].x; s2 += w[o + 7].y - w[o].y; }
      }
      #pragma unroll
      for (int op = 0; op < 4; ++op) {
        unsigned int lo32 = pack_bf2(nrmv[2 * op], nrmv[2 * op + 1]);
        float h0, h1;
        if (phase == 0) { h0 = xv[2 * op]; h1 = xv[2 * op + 1]; }
        else {
          h0 = nrmv[2 * op]     * sdR[2 * op]     + meanR[2 * op];
          h1 = nrmv[2 * op + 1] * sdR[2 * op + 1] + meanR[2 * op + 1];
        }
        unsigned int hi32 = pack_bf2(h0, h1);
        int m = (c0 >> 1) + op;                  // u32-pair column 0..63
        obI[r * 64 + ((m + r) & 63)] = ((unsigned long long)hi32 << 32) | lo32;
      }
    }
    __syncthreads();
    {
      int r  = t >> 4;
      int mg = (t & 15) * 4;
      unsigned int t0[4], t1[4];
      #pragma unroll
      for (int k2 = 0; k2 < 4; ++k2) {
        unsigned long long v = obI[r * 64 + ((mg + k2 + r) & 63)];
        t0[k2] = (unsigned int)v;
        t1[k2] = (unsigned int)(v >> 32);
      }
      // tiled store: p -> (pt = p>>6, pxi = p&63); addr = ((b*256+pt)*256+c)*64+pxi
      int p = (r0 + r) * 128 + mg * 2;
      size_t gb2 = (((size_t)(b * 256 + (p >> 6))) * 256 + c) * 64 + (p & 63);
      int tn0 = (phase == 0) ? 1 : 0;
      int tn1 = (phase == 0) ? 3 : 2;
      *(uint4v*)(xcm + (size_t)tn0 * TSZ + gb2) = (uint4v){t0[0], t0[1], t0[2], t0[3]};
      *(uint4v*)(xcm + (size_t)tn1 * TSZ + gb2) = (uint4v){t1[0], t1[1], t1[2], t1[3]};
    }
  }
}

// ---------------------------------------------------------------------------
// Kernel 2: four fused conv1x1 GEMMs per 64-pixel tile via bf16 MFMA.
// R3: same counted-vmcnt 5-buffer pipeline as R2, but both operand streams
// are now layout-packed so every VMEM instruction is a contiguous wave-1KB
// (weights) or contiguous wave-1KB slice of a contiguous 4KB tile (X stage)
// -> ~16x fewer L2 requests; the depth-3 prefetch can actually fill.
// ---------------------------------------------------------------------------
#define SB0   __builtin_amdgcn_sched_barrier(0)
#define BARR  __builtin_amdgcn_s_barrier()
#define LGKM0 asm volatile("s_waitcnt lgkmcnt(0)" ::: "memory")
#define VMC(n) asm volatile("s_waitcnt vmcnt(" #n ")" ::: "memory")

__device__ __forceinline__ void stage_tile(const unsigned short* __restrict__ Xt,
                                           int k0, int t,
                                           unsigned short* dst) {
  // LDS 16B-chunk t holds subtile element: k = (t>>5)*4 + ((t&7)>>1),
  // px = ((t>>3)&3)*16 + (t&1)*8.  Source tile is contiguous [k][px] 4KB.
  int kk = ((t >> 5) << 2) + ((t & 7) >> 1);
  int px = (((t >> 3) & 3) << 4) + ((t & 1) << 3);
  const unsigned short* src = Xt + (size_t)(k0 << 6) + (kk << 6) + px;
  typedef const __attribute__((address_space(1))) unsigned int GUI;
  typedef __attribute__((address_space(3))) unsigned int LUI;
  __builtin_amdgcn_global_load_lds((GUI*)(unsigned long long)src,
                                   (LUI*)(unsigned)(unsigned long long)(dst + t * 8),
                                   16, 0, 0);
}

// packed weights: af[S][im] <- Wr + I*8192 + im*512  (lane-linear 1KB/instr)
#define LOADA(S, I) {                                           \
  af[S][0] = *(const short8*)(Wr + (I) * 8192 + 0 * 512);       \
  af[S][1] = *(const short8*)(Wr + (I) * 8192 + 1 * 512);       \
  af[S][2] = *(const short8*)(Wr + (I) * 8192 + 2 * 512);       \
  af[S][3] = *(const short8*)(Wr + (I) * 8192 + 3 * 512); }

#define TR8(O0,O1,O2,O3,O4,O5,O6,O7)                                              \
  asm volatile("ds_read_b64_tr_b16 %0, %1 offset:" #O0 : "=v"(r0) : "v"(tra));    \
  asm volatile("ds_read_b64_tr_b16 %0, %1 offset:" #O1 : "=v"(r1) : "v"(tra));    \
  asm volatile("ds_read_b64_tr_b16 %0, %1 offset:" #O2 : "=v"(r2) : "v"(tra));    \
  asm volatile("ds_read_b64_tr_b16 %0, %1 offset:" #O3 : "=v"(r3) : "v"(tra));    \
  asm volatile("ds_read_b64_tr_b16 %0, %1 offset:" #O4 : "=v"(r4) : "v"(tra));    \
  asm volatile("ds_read_b64_tr_b16 %0, %1 offset:" #O5 : "=v"(r5) : "v"(tra));    \
  asm volatile("ds_read_b64_tr_b16 %0, %1 offset:" #O6 : "=v"(r6) : "v"(tra));    \
  asm volatile("ds_read_b64_tr_b16 %0, %1 offset:" #O7 : "=v"(r7) : "v"(tra));

#define DOMFMA(MS) {                                                        \
  union BU { unsigned u[4]; short8 s; } bu0, bu1, bu2, bu3;                 \
  bu0.u[0]=r0[0]; bu0.u[1]=r0[1]; bu0.u[2]=r1[0]; bu0.u[3]=r1[1];           \
  bu1.u[0]=r2[0]; bu1.u[1]=r2[1]; bu1.u[2]=r3[0]; bu1.u[3]=r3[1];           \
  bu2.u[0]=r4[0]; bu2.u[1]=r4[1]; bu2.u[2]=r5[0]; bu2.u[3]=r5[1];           \
  bu3.u[0]=r6[0]; bu3.u[1]=r6[1]; bu3.u[2]=r7[0]; bu3.u[3]=r7[1];           \
  short8 bv0 = bu0.s, bv1 = bu1.s, bv2 = bu2.s, bv3 = bu3.s;                \
  _Pragma("unroll")                                                         \
  for (int im = 0; im < 4; ++im) {                                          \
    acc[0][im] = __builtin_amdgcn_mfma_f32_16x16x32_bf16(af[MS][im], bv0, acc[0][im], 0, 0, 0); \
    acc[1][im] = __builtin_amdgcn_mfma_f32_16x16x32_bf16(af[MS][im], bv1, acc[1][im], 0, 0, 0); \
    acc[2][im] = __builtin_amdgcn_mfma_f32_16x16x32_bf16(af[MS][im], bv2, acc[2][im], 0, 0, 0); \
    acc[3][im] = __builtin_amdgcn_mfma_f32_16x16x32_bf16(af[MS][im], bv3, acc[3][im], 0, 0, 0); \
  } }

// one K-step: optional stage (depth-3), optional A prefetch (2 ahead),
// counted vmcnt, barrier, tr-reads of buf i, MFMA.
#define GSTEP(VN, DOSTAGE, K0, SLOT, DOA, AS, AI, MS, O0,O1,O2,O3,O4,O5,O6,O7) \
  SB0;                                                                          \
  if (DOSTAGE) stage_tile(X, K0, t, xt + (SLOT) * 2048);                        \
  SB0;                                                                          \
  if (DOA) LOADA(AS, AI);                                                       \
  SB0;                                                                          \
  VMC(VN);                                                                      \
  SB0; BARR; SB0;                                                               \
  TR8(O0,O1,O2,O3,O4,O5,O6,O7);                                                 \
  LGKM0; SB0;                                                                   \
  DOMFMA(MS);

__device__ __forceinline__ void gemm_pipe(const unsigned short* __restrict__ X,
                                          const unsigned short* __restrict__ Wm,
                                          unsigned short* xt, unsigned xbase,
                                          int mbase, int lane, int t,
                                          float4v acc[4][4]) {
  unsigned tra = xbase + (unsigned)((((lane >> 4)) << 10) + ((lane & 15) << 3));
  // packed weights: Wr = Wm + wv*2048 + lane*8
  const unsigned short* __restrict__ Wr = Wm + ((mbase >> 6) << 11) + lane * 8;

  short8 af[3][4];
  uint2v r0, r1, r2, r3, r4, r5, r6, r7;

  #pragma unroll
  for (int in = 0; in < 4; ++in)
    #pragma unroll
    for (int im = 0; im < 4; ++im)
      acc[in][im] = (float4v){0.f, 0.f, 0.f, 0.f};

  // top barrier: all waves done reading slots of the previous gemm
  SB0; BARR; SB0;
  stage_tile(X,  0, t, xt + 0 * 2048);
  stage_tile(X, 32, t, xt + 1 * 2048);
  stage_tile(X, 64, t, xt + 2 * 2048);
  SB0;
  LOADA(0, 0);
  SB0;
  LOADA(1, 1);
  SB0;

  //     VN  st  K0  slot  A  AS AI MS   tr offsets (slot*4096 + subtile)
  GSTEP( 9,  1,  96,  3,   1, 2, 2, 0,      0,  512,  128,  640,  256,  768,  384,  896)
  GSTEP(10,  1, 128,  4,   1, 0, 3, 1,   4096, 4608, 4224, 4736, 4352, 4864, 4480, 4992)
  GSTEP(10,  1, 160,  0,   1, 1, 4, 2,   8192, 8704, 8320, 8832, 8448, 8960, 8576, 9088)
  GSTEP(10,  1, 192,  1,   1, 2, 5, 0,  12288,12800,12416,12928,12544,13056,12672,13184)
  GSTEP(10,  1, 224,  2,   1, 0, 6, 1,  16384,16896,16512,17024,16640,17152,16768,17280)
  GSTEP( 9,  0,   0,  0,   1, 1, 7, 2,      0,  512,  128,  640,  256,  768,  384,  896)
  GSTEP( 4,  0,   0,  0,   0, 0, 0, 0,   4096, 4608, 4224, 4736, 4352, 4864, 4480, 4992)
  GSTEP( 0,  0,   0,  0,   0, 0, 0, 1,   8192, 8704, 8320, 8832, 8448, 8960, 8576, 9088)
}

__global__ __launch_bounds__(256, 2) void k_gemm(const unsigned short* __restrict__ xcm,
                                                 const unsigned short* __restrict__ wbf,
                                                 const float* __restrict__ bFF,
                                                 const float* __restrict__ bGG,
                                                 const float* __restrict__ bEE,
                                                 const float* __restrict__ bHH,
                                                 unsigned short* __restrict__ eecm,
                                                 unsigned short* __restrict__ hhcm,
                                                 float* __restrict__ Sout) {
  int blk  = blockIdx.x;
  int b    = blk >> 8;
  int pt   = blk & 255;
  int p0   = pt * 64;
  int t    = threadIdx.x;
  int wv   = t >> 6;
  int lane = t & 63;
  int col  = lane & 15;
  int q    = lane >> 4;
  int mbase = wv * 64;

  __shared__ __align__(16) unsigned short xt[5][2048];   // 20 KB: 5 X buffers
  __shared__ float sred[3 * 64];       // dot, |F|^2, |G|^2 per pixel
  if (t < 192) sred[t] = 0.f;
  __syncthreads();
  unsigned xbase = (unsigned)(unsigned long long)&xt[0][0];

  // contiguous X tile base for this (b, pt): xcm2[tens][b][pt][k][px]
  const unsigned short* Xt = xcm + (((size_t)(b * 256 + pt)) << 14);

  float4v aF[4][4], aG[4][4];

  // FF = wf * front_norm + bf ; GG = wg * back_norm + bg
  gemm_pipe(Xt + 0 * TSZ, wbf + 0 * 65536, &xt[0][0], xbase, mbase, lane, t, aF);
  gemm_pipe(Xt + 1 * TSZ, wbf + 1 * 65536, &xt[0][0], xbase, mbase, lane, t, aG);
  #pragma unroll
  for (int im = 0; im < 4; ++im) {
    float4v bvF = *(const float4v*)(bFF + mbase + im * 16 + q * 4);
    float4v bvG = *(const float4v*)(bGG + mbase + im * 16 + q * 4);
    #pragma unroll
    for (int in = 0; in < 4; ++in) { aF[in][im] += bvF; aG[in][im] += bvG; }
  }
  // cosine partials: lane-local over 16 m's, then quad shuffle, then LDS
  #pragma unroll
  for (int in = 0; in < 4; ++in) {
    float d = 0.f, nf = 0.f, ng = 0.f;
    #pragma unroll
    for (int im = 0; im < 4; ++im)
      #pragma unroll
      for (int r = 0; r < 4; ++r) {
        float f = aF[in][im][r], g = aG[in][im][r];
        d += f * g; nf += f * f; ng += g * g;
      }
    d  += __shfl_xor(d, 16);  d  += __shfl_xor(d, 32);
    nf += __shfl_xor(nf, 16); nf += __shfl_xor(nf, 32);
    ng += __shfl_xor(ng, 16); ng += __shfl_xor(ng, 32);
    if (lane < 16) {
      atomicAdd(&sred[0 * 64 + in * 16 + lane], d);
      atomicAdd(&sred[1 * 64 + in * 16 + lane], nf);
      atomicAdd(&sred[2 * 64 + in * 16 + lane], ng);
    }
  }
  // EE = we * adain + be  -> store bf16 channel-major
  gemm_pipe(Xt + 2 * TSZ, wbf + 2 * 65536, &xt[0][0], xbase, mbase, lane, t, aF);
  #pragma unroll
  for (int im = 0; im < 4; ++im) {
    float4v bv = *(const float4v*)(bEE + mbase + im * 16 + q * 4);
    #pragma unroll
    for (int in = 0; in < 4; ++in)
      #pragma unroll
      for (int r = 0; r < 4; ++r) {
        int m = mbase + im * 16 + q * 4 + r;
        eecm[((size_t)(b * 256 + m)) * PIX + p0 + in * 16 + col] = f2bf(aF[in][im][r] + bv[r]);
      }
  }
  // HH = wh * back + bh
  gemm_pipe(Xt + 3 * TSZ, wbf + 3 * 65536, &xt[0][0], xbase, mbase, lane, t, aG);
  #pragma unroll
  for (int im = 0; im < 4; ++im) {
    float4v bv = *(const float4v*)(bHH + mbase + im * 16 + q * 4);
    #pragma unroll
    for (int in = 0; in < 4; ++in)
      #pragma unroll
      for (int r = 0; r < 4; ++r) {
        int m = mbase + im * 16 + q * 4 + r;
        hhcm[((size_t)(b * 256 + m)) * PIX + p0 + in * 16 + col] = f2bf(aG[in][im][r] + bv[r]);
      }
  }
  __syncthreads();
  if (t < 64) {
    float d = sred[t], nf = sred[64 + t], ng = sred[128 + t];
    Sout[(size_t)b * PIX + p0 + t] = d / (sqrtf(nf) * sqrtf(ng));
  }
}

// ---------------------------------------------------------------------------
// Kernel 3: per-batch min/max of S (one block per batch)
// ---------------------------------------------------------------------------
__global__ __launch_bounds__(256) void k_minmax(const float* __restrict__ S,
                                                float* __restrict__ mm) {
  int b = blockIdx.x, t = threadIdx.x;
  const float* sp = S + (size_t)b * PIX;
  float mn = 3.0e38f, mx = -3.0e38f;
  for (int i = t; i < PIX; i += 256) { float v = sp[i]; mn = fminf(mn, v); mx = fmaxf(mx, v); }
  #pragma unroll
  for (int o = 32; o >= 1; o >>= 1) {
    mn = fminf(mn, __shfl_xor(mn, o));
    mx = fmaxf(mx, __shfl_xor(mx, o));
  }
  __shared__ float smn[4], smx[4];
  if ((t & 63) == 0) { smn[t >> 6] = mn; smx[t >> 6] = mx; }
  __syncthreads();
  if (t == 0) {
    mn = fminf(fminf(smn[0], smn[1]), fminf(smn[2], smn[3]));
    mx = fmaxf(fmaxf(smx[0], smx[1]), fmaxf(smx[2], smx[3]));
    mm[b * 2] = mn; mm[b * 2 + 1] = mx;
  }
}

// ---------------------------------------------------------------------------
// Kernel 4: fused = S_n*EE + (1-S_n)*HH.  4 px/thread, every store/load
// lane-contiguous (float4 out, uint2 bf16 in, float4 S in).
// ---------------------------------------------------------------------------
__global__ __launch_bounds__(256) void k_blend(const unsigned short* __restrict__ ee,
                                               const unsigned short* __restrict__ hh,
                                               const float* __restrict__ S,
                                               const float* __restrict__ mm,
                                               float* __restrict__ out) {
  size_t base = ((size_t)blockIdx.x * 256 + threadIdx.x) * 4;
  int b = (int)(base >> 22);            // / (256*16384)
  int p = (int)(base & 16383);
  float mn = mm[b * 2], mx = mm[b * 2 + 1];
  float inv = 1.f / (mx - mn);
  uint2v eu = *(const uint2v*)(ee + base);
  uint2v hu = *(const uint2v*)(hh + base);
  float4v s0 = *(const float4v*)(S + ((size_t)b << 14) + p);
  float ov[4];
  #pragma unroll
  for (int i = 0; i < 2; ++i) {
    unsigned int ew = eu[i], hw = hu[i];
    float e0 = bf2f((unsigned short)(ew & 0xffffu));
    float e1 = bf2f((unsigned short)(ew >> 16));
    float h0 = bf2f((unsigned short)(hw & 0xffffu));
    float h1 = bf2f((unsigned short)(hw >> 16));
    float a0 = (s0[2 * i] - mn) * inv;
    float a1 = (s0[2 * i + 1] - mn) * inv;
    ov[2 * i]     = h0 + a0 * (e0 - h0);
    ov[2 * i + 1] = h1 + a1 * (e1 - h1);
  }
  *(float4v*)(out + base) = (float4v){ov[0], ov[1], ov[2], ov[3]};
}

// ---------------------------------------------------------------------------
// Workspace layout (bytes):
//   0          : xcm   4 tensors bf16 (tiled)    = 268,435,456
//   268435456  : wbf   4x256x256 bf16 (packed)   =     524,288
//   268959744  : eecm  bf16                      =  67,108,864
//   336068608  : hhcm  bf16                      =  67,108,864
//   403177472  : S     fp32 8x16384              =     524,288
//   403701760  : mm    fp32 8x2                  =          64
// total ~403.7 MB
// ---------------------------------------------------------------------------
extern "C" void kernel_launch(void* const* d_in, const int* in_sizes, int n_in,
                              void* d_out, int out_size, void* d_ws, size_t ws_size,
                              hipStream_t stream) {
  const float* front = (const float*)d_in[0];
  const float* back  = (const float*)d_in[1];
  // d_in[2] = mask (unused by reference)
  const float* we = (const float*)d_in[3];
  const float* be = (const float*)d_in[4];
  const float* wf = (const float*)d_in[5];
  const float* bf = (const float*)d_in[6];
  const float* wg = (const float*)d_in[7];
  const float* bg = (const float*)d_in[8];
  const float* wh = (const float*)d_in[9];
  const float* bh = (const float*)d_in[10];

  char* ws = (char*)d_ws;
  unsigned short* xcm  = (unsigned short*)(ws);
  unsigned short* wbf  = (unsigned short*)(ws + 268435456);
  unsigned short* eecm = (unsigned short*)(ws + 268959744);
  unsigned short* hhcm = (unsigned short*)(ws + 336068608);
  float*          S    = (float*)(ws + 403177472);
  float*          mm   = (float*)(ws + 403701760);
  float*          out  = (float*)d_out;

  k_prep  <<<1024,  256, 0, stream>>>(we, wf, wg, wh, wbf);
  k_stats <<<16384, 256, 0, stream>>>(front, back, xcm);
  k_gemm  <<<2048,  256, 0, stream>>>(xcm, wbf, bf, bg, be, bh, eecm, hhcm, S);
  k_minmax<<<8,     256, 0, stream>>>(S, mm);
  k_blend <<<32768, 256, 0, stream>>>(eecm, hhcm, S, mm, out);
}

// Round 4
// 522.748 us; speedup vs baseline: 1.3592x; 1.1349x over previous
//
#include <hip/hip_runtime.h>
#include <math.h>

// Problem constants: B=8, C=256, H=W=128
#define PIX 16384                       // H*W
#define TSZ ((size_t)33554432)          // 8*256*16384 elements per tensor

typedef __attribute__((ext_vector_type(8))) short  short8;   // 8 x bf16 (4 VGPRs)
typedef __attribute__((ext_vector_type(4))) float  float4v;
typedef __attribute__((ext_vector_type(4))) unsigned int uint4v;
typedef __attribute__((ext_vector_type(2))) unsigned int uint2v;

__device__ __forceinline__ unsigned short f2bf(float x) {
  unsigned int u = __float_as_uint(x);
  u += 0x7fffu + ((u >> 16) & 1u);      // round-to-nearest-even
  return (unsigned short)(u >> 16);
}
__device__ __forceinline__ float bf2f(unsigned short h) {
  return __uint_as_float(((unsigned int)h) << 16);
}
// pack two fp32 -> (bf16(hi)<<16)|bf16(lo) via v_perm_b32
__device__ __forceinline__ unsigned int pack_bf2(float lo, float hi) {
  unsigned int ul = __float_as_uint(lo); ul += 0x7fffu + ((ul >> 16) & 1u);
  unsigned int uh = __float_as_uint(hi); uh += 0x7fffu + ((uh >> 16) & 1u);
  return __builtin_amdgcn_perm(uh, ul, 0x07060302u);  // [ul.b2,ul.b3,uh.b2,uh.b3]
}

// ---------------------------------------------------------------------------
// Kernel 0: weights -> bf16, PACKED for lane-linear 1KB wave loads.
// Layout (shorts): wpk[g][i=kstep(8)][wv(4)][im(4)][lane(64)][e(8)]
//   lane=(q<<4)|col;  m = wv*64+im*16+col;  k = i*32+q*8+e
// Conv order: 0=FF(wf), 1=GG(wg), 2=EE(we), 3=HH(wh)
// ---------------------------------------------------------------------------
__global__ __launch_bounds__(256) void k_prep(const float* __restrict__ we,
                                              const float* __restrict__ wf,
                                              const float* __restrict__ wg,
                                              const float* __restrict__ wh,
                                              unsigned short* __restrict__ wbf) {
  int idx = blockIdx.x * 256 + threadIdx.x;      // 0 .. 262143
  int g = idx >> 16, within = idx & 65535;
  const float* src = (g == 0) ? wf : (g == 1) ? wg : (g == 2) ? we : wh;
  int e    = within & 7;
  int lane = (within >> 3) & 63;
  int im   = (within >> 9) & 3;
  int wv   = (within >> 11) & 3;
  int i    = within >> 13;
  int col = lane & 15, q = lane >> 4;
  int m = wv * 64 + im * 16 + col;
  int k = i * 32 + q * 8 + e;
  wbf[idx] = f2bf(src[m * 256 + k]);
}

// ---------------------------------------------------------------------------
// Kernel 1: 7x7 patch stats (zero-padded box sums), normalization, adain.
// Output TILED: xcm[tens][b][pt(256)][k=c(256)][px(64)] bf16 (contiguous
// 4KB stage tiles for the gemms). Unchanged this round.
// ---------------------------------------------------------------------------
__global__ __launch_bounds__(256, 4) void k_stats(const float* __restrict__ front,
                                                  const float* __restrict__ back,
                                                  unsigned short* __restrict__ xcm) {
  int blk = blockIdx.x;
  int s   = blk & 7;            // strip (16 rows)
  int c   = (blk >> 3) & 255;
  int b   = blk >> 11;
  int t   = threadIdx.x;
  int r0  = s * 16;

  __shared__ float  xs[22 * 129];
  __shared__ float2 vsp[16 * 131];
  __shared__ unsigned long long obI[16 * 64];

  size_t planeOff = ((size_t)(b * 256 + c)) * PIX;

  float meanR[8], sdR[8];       // back stats, phase0 -> phase1 carry

  #pragma unroll 1
  for (int phase = 0; phase < 2; ++phase) {     // 0 = back, 1 = front
    const float* src = (phase == 0 ? back : front) + planeOff;
    #pragma unroll
    for (int i = 0; i < 3; ++i) {
      int idx = t + i * 256;                     // 704 = 22*32 float4s
      if (idx < 704) {
        int l = idx >> 5, cv = (idx & 31) * 4;
        int g = r0 - 3 + l;
        float4v v = {0.f, 0.f, 0.f, 0.f};
        if (g >= 0 && g < 128) v = *(const float4v*)(src + g * 128 + cv);
        xs[l * 129 + cv]     = v[0];
        xs[l * 129 + cv + 1] = v[1];
        xs[l * 129 + cv + 2] = v[2];
        xs[l * 129 + cv + 3] = v[3];
      }
    }
    __syncthreads();
    {
      int col = t & 127;
      int rg  = (t >> 7) * 8;                    // 8 output rows per thread
      float sm = 0.f, s2 = 0.f;
      #pragma unroll
      for (int j = 0; j < 7; ++j) { float v = xs[(rg + j) * 129 + col]; sm += v; s2 = fmaf(v, v, s2); }
      vsp[rg * 131 + col] = make_float2(sm, s2);
      #pragma unroll
      for (int o = 1; o < 8; ++o) {
        float vn = xs[(rg + o + 6) * 129 + col];
        float vo = xs[(rg + o - 1) * 129 + col];
        sm += vn - vo;
        s2 += vn * vn - vo * vo;
        vsp[(rg + o) * 131 + col] = make_float2(sm, s2);
      }
    }
    __syncthreads();
    {
      int r  = t & 15;
      int c0 = (t >> 4) * 8;                     // 8 output cols per thread
      float2 w[14];
      #pragma unroll
      for (int i = 0; i < 14; ++i) {
        int cc = c0 - 3 + i;
        float2 v = make_float2(0.f, 0.f);
        if (cc >= 0 && cc < 128) v = vsp[r * 131 + cc];
        w[i] = v;
      }
      float sm = 0.f, s2 = 0.f;
      #pragma unroll
      for (int i = 0; i < 7; ++i) { sm += w[i].x; s2 += w[i].y; }
      float nrmv[8], xv[8];
      #pragma unroll
      for (int o = 0; o < 8; ++o) {
        float mean = sm * (1.f / 49.f);
        float var  = (s2 - sm * mean) * (1.f / 48.f);   // (s2 - s^2/49)/48
        var = var > 0.f ? var : 0.f;
        float sd = __builtin_amdgcn_sqrtf(var);
        float x  = xs[(r + 3) * 129 + c0 + o];
        float nrm = (x - mean) * __builtin_amdgcn_rcpf(sd + 1e-8f);
        if (phase == 0) { meanR[o] = mean; sdR[o] = sd; }
        nrmv[o] = nrm; xv[o] = x;
        if (o < 7) { sm += w[o + 7].x - w[o].x; s2 += w[o + 7].y - w[o].y; }
      }
      #pragma unroll
      for (int op = 0; op < 4; ++op) {
        unsigned int lo32 = pack_bf2(nrmv[2 * op], nrmv[2 * op + 1]);
        float h0, h1;
        if (phase == 0) { h0 = xv[2 * op]; h1 = xv[2 * op + 1]; }
        else {
          h0 = nrmv[2 * op]     * sdR[2 * op]     + meanR[2 * op];
          h1 = nrmv[2 * op + 1] * sdR[2 * op + 1] + meanR[2 * op + 1];
        }
        unsigned int hi32 = pack_bf2(h0, h1);
        int m = (c0 >> 1) + op;                  // u32-pair column 0..63
        obI[r * 64 + ((m + r) & 63)] = ((unsigned long long)hi32 << 32) | lo32;
      }
    }
    __syncthreads();
    {
      int r  = t >> 4;
      int mg = (t & 15) * 4;
      unsigned int t0[4], t1[4];
      #pragma unroll
      for (int k2 = 0; k2 < 4; ++k2) {
        unsigned long long v = obI[r * 64 + ((mg + k2 + r) & 63)];
        t0[k2] = (unsigned int)v;
        t1[k2] = (unsigned int)(v >> 32);
      }
      // tiled store: p -> (pt = p>>6, pxi = p&63); addr = ((b*256+pt)*256+c)*64+pxi
      int p = (r0 + r) * 128 + mg * 2;
      size_t gb2 = (((size_t)(b * 256 + (p >> 6))) * 256 + c) * 64 + (p & 63);
      int tn0 = (phase == 0) ? 1 : 0;
      int tn1 = (phase == 0) ? 3 : 2;
      *(uint4v*)(xcm + (size_t)tn0 * TSZ + gb2) = (uint4v){t0[0], t0[1], t0[2], t0[3]};
      *(uint4v*)(xcm + (size_t)tn1 * TSZ + gb2) = (uint4v){t1[0], t1[1], t1[2], t1[3]};
    }
  }
}

// ---------------------------------------------------------------------------
// GEMM machinery (R3's counted-vmcnt 5-buffer pipeline, packed operands).
// ---------------------------------------------------------------------------
#define SB0   __builtin_amdgcn_sched_barrier(0)
#define BARR  __builtin_amdgcn_s_barrier()
#define LGKM0 asm volatile("s_waitcnt lgkmcnt(0)" ::: "memory")
#define VMC(n) asm volatile("s_waitcnt vmcnt(" #n ")" ::: "memory")

__device__ __forceinline__ void stage_tile(const unsigned short* __restrict__ Xt,
                                           int k0, int t,
                                           unsigned short* dst) {
  // LDS 16B-chunk t holds subtile element: k = (t>>5)*4 + ((t&7)>>1),
  // px = ((t>>3)&3)*16 + (t&1)*8.  Source tile is contiguous [k][px] 4KB.
  int kk = ((t >> 5) << 2) + ((t & 7) >> 1);
  int px = (((t >> 3) & 3) << 4) + ((t & 1) << 3);
  const unsigned short* src = Xt + (size_t)(k0 << 6) + (kk << 6) + px;
  typedef const __attribute__((address_space(1))) unsigned int GUI;
  typedef __attribute__((address_space(3))) unsigned int LUI;
  __builtin_amdgcn_global_load_lds((GUI*)(unsigned long long)src,
                                   (LUI*)(unsigned)(unsigned long long)(dst + t * 8),
                                   16, 0, 0);
}

// packed weights: af[S][im] <- Wr + I*8192 + im*512  (lane-linear 1KB/instr)
#define LOADA(S, I) {                                           \
  af[S][0] = *(const short8*)(Wr + (I) * 8192 + 0 * 512);       \
  af[S][1] = *(const short8*)(Wr + (I) * 8192 + 1 * 512);       \
  af[S][2] = *(const short8*)(Wr + (I) * 8192 + 2 * 512);       \
  af[S][3] = *(const short8*)(Wr + (I) * 8192 + 3 * 512); }

#define TR8(O0,O1,O2,O3,O4,O5,O6,O7)                                              \
  asm volatile("ds_read_b64_tr_b16 %0, %1 offset:" #O0 : "=v"(r0) : "v"(tra));    \
  asm volatile("ds_read_b64_tr_b16 %0, %1 offset:" #O1 : "=v"(r1) : "v"(tra));    \
  asm volatile("ds_read_b64_tr_b16 %0, %1 offset:" #O2 : "=v"(r2) : "v"(tra));    \
  asm volatile("ds_read_b64_tr_b16 %0, %1 offset:" #O3 : "=v"(r3) : "v"(tra));    \
  asm volatile("ds_read_b64_tr_b16 %0, %1 offset:" #O4 : "=v"(r4) : "v"(tra));    \
  asm volatile("ds_read_b64_tr_b16 %0, %1 offset:" #O5 : "=v"(r5) : "v"(tra));    \
  asm volatile("ds_read_b64_tr_b16 %0, %1 offset:" #O6 : "=v"(r6) : "v"(tra));    \
  asm volatile("ds_read_b64_tr_b16 %0, %1 offset:" #O7 : "=v"(r7) : "v"(tra));

#define DOMFMA(MS) {                                                        \
  union BU { unsigned u[4]; short8 s; } bu0, bu1, bu2, bu3;                 \
  bu0.u[0]=r0[0]; bu0.u[1]=r0[1]; bu0.u[2]=r1[0]; bu0.u[3]=r1[1];           \
  bu1.u[0]=r2[0]; bu1.u[1]=r2[1]; bu1.u[2]=r3[0]; bu1.u[3]=r3[1];           \
  bu2.u[0]=r4[0]; bu2.u[1]=r4[1]; bu2.u[2]=r5[0]; bu2.u[3]=r5[1];           \
  bu3.u[0]=r6[0]; bu3.u[1]=r6[1]; bu3.u[2]=r7[0]; bu3.u[3]=r7[1];           \
  short8 bv0 = bu0.s, bv1 = bu1.s, bv2 = bu2.s, bv3 = bu3.s;                \
  _Pragma("unroll")                                                         \
  for (int im = 0; im < 4; ++im) {                                          \
    acc[0][im] = __builtin_amdgcn_mfma_f32_16x16x32_bf16(af[MS][im], bv0, acc[0][im], 0, 0, 0); \
    acc[1][im] = __builtin_amdgcn_mfma_f32_16x16x32_bf16(af[MS][im], bv1, acc[1][im], 0, 0, 0); \
    acc[2][im] = __builtin_amdgcn_mfma_f32_16x16x32_bf16(af[MS][im], bv2, acc[2][im], 0, 0, 0); \
    acc[3][im] = __builtin_amdgcn_mfma_f32_16x16x32_bf16(af[MS][im], bv3, acc[3][im], 0, 0, 0); \
  } }

// one K-step: optional stage (depth-3), optional A prefetch (2 ahead),
// counted vmcnt, barrier, tr-reads of buf i, MFMA.
#define GSTEP(VN, DOSTAGE, K0, SLOT, DOA, AS, AI, MS, O0,O1,O2,O3,O4,O5,O6,O7) \
  SB0;                                                                          \
  if (DOSTAGE) stage_tile(X, K0, t, xt + (SLOT) * 2048);                        \
  SB0;                                                                          \
  if (DOA) LOADA(AS, AI);                                                       \
  SB0;                                                                          \
  VMC(VN);                                                                      \
  SB0; BARR; SB0;                                                               \
  TR8(O0,O1,O2,O3,O4,O5,O6,O7);                                                 \
  LGKM0; SB0;                                                                   \
  DOMFMA(MS);

__device__ __forceinline__ void gemm_pipe(const unsigned short* __restrict__ X,
                                          const unsigned short* __restrict__ Wm,
                                          unsigned short* xt, unsigned xbase,
                                          int mbase, int lane, int t,
                                          float4v acc[4][4]) {
  unsigned tra = xbase + (unsigned)((((lane >> 4)) << 10) + ((lane & 15) << 3));
  // packed weights: Wr = Wm + wv*2048 + lane*8
  const unsigned short* __restrict__ Wr = Wm + ((mbase >> 6) << 11) + lane * 8;

  short8 af[3][4];
  uint2v r0, r1, r2, r3, r4, r5, r6, r7;

  #pragma unroll
  for (int in = 0; in < 4; ++in)
    #pragma unroll
    for (int im = 0; im < 4; ++im)
      acc[in][im] = (float4v){0.f, 0.f, 0.f, 0.f};

  // top barrier: all waves done reading slots of the previous gemm
  SB0; BARR; SB0;
  stage_tile(X,  0, t, xt + 0 * 2048);
  stage_tile(X, 32, t, xt + 1 * 2048);
  stage_tile(X, 64, t, xt + 2 * 2048);
  SB0;
  LOADA(0, 0);
  SB0;
  LOADA(1, 1);
  SB0;

  //     VN  st  K0  slot  A  AS AI MS   tr offsets (slot*4096 + subtile)
  GSTEP( 9,  1,  96,  3,   1, 2, 2, 0,      0,  512,  128,  640,  256,  768,  384,  896)
  GSTEP(10,  1, 128,  4,   1, 0, 3, 1,   4096, 4608, 4224, 4736, 4352, 4864, 4480, 4992)
  GSTEP(10,  1, 160,  0,   1, 1, 4, 2,   8192, 8704, 8320, 8832, 8448, 8960, 8576, 9088)
  GSTEP(10,  1, 192,  1,   1, 2, 5, 0,  12288,12800,12416,12928,12544,13056,12672,13184)
  GSTEP(10,  1, 224,  2,   1, 0, 6, 1,  16384,16896,16512,17024,16640,17152,16768,17280)
  GSTEP( 9,  0,   0,  0,   1, 1, 7, 2,      0,  512,  128,  640,  256,  768,  384,  896)
  GSTEP( 4,  0,   0,  0,   0, 0, 0, 0,   4096, 4608, 4224, 4736, 4352, 4864, 4480, 4992)
  GSTEP( 0,  0,   0,  0,   0, 0, 0, 1,   8192, 8704, 8320, 8832, 8448, 8960, 8576, 9088)
}

// ---------------------------------------------------------------------------
// Kernel 2a: FF/GG gemms -> cosine similarity S.  (EE/HH moved to k_gemm2.)
// ---------------------------------------------------------------------------
__global__ __launch_bounds__(256, 2) void k_gemm1(const unsigned short* __restrict__ xcm,
                                                  const unsigned short* __restrict__ wbf,
                                                  const float* __restrict__ bFF,
                                                  const float* __restrict__ bGG,
                                                  float* __restrict__ Sout) {
  int blk  = blockIdx.x;
  int b    = blk >> 8;
  int pt   = blk & 255;
  int p0   = pt * 64;
  int t    = threadIdx.x;
  int wv   = t >> 6;
  int lane = t & 63;
  int q    = lane >> 4;
  int mbase = wv * 64;

  __shared__ __align__(16) unsigned short xt[5][2048];   // 20 KB: 5 X buffers
  __shared__ float sred[3 * 64];       // dot, |F|^2, |G|^2 per pixel
  if (t < 192) sred[t] = 0.f;
  __syncthreads();
  unsigned xbase = (unsigned)(unsigned long long)&xt[0][0];

  // contiguous X tile base for this (b, pt): xcm[tens][b][pt][k][px]
  const unsigned short* Xt = xcm + (((size_t)(b * 256 + pt)) << 14);

  float4v aF[4][4], aG[4][4];

  gemm_pipe(Xt + 0 * TSZ, wbf + 0 * 65536, &xt[0][0], xbase, mbase, lane, t, aF);
  gemm_pipe(Xt + 1 * TSZ, wbf + 1 * 65536, &xt[0][0], xbase, mbase, lane, t, aG);
  #pragma unroll
  for (int im = 0; im < 4; ++im) {
    float4v bvF = *(const float4v*)(bFF + mbase + im * 16 + q * 4);
    float4v bvG = *(const float4v*)(bGG + mbase + im * 16 + q * 4);
    #pragma unroll
    for (int in = 0; in < 4; ++in) { aF[in][im] += bvF; aG[in][im] += bvG; }
  }
  // cosine partials: lane-local over 16 m's, then quad shuffle, then LDS
  #pragma unroll
  for (int in = 0; in < 4; ++in) {
    float d = 0.f, nf = 0.f, ng = 0.f;
    #pragma unroll
    for (int im = 0; im < 4; ++im)
      #pragma unroll
      for (int r = 0; r < 4; ++r) {
        float f = aF[in][im][r], g = aG[in][im][r];
        d += f * g; nf += f * f; ng += g * g;
      }
    d  += __shfl_xor(d, 16);  d  += __shfl_xor(d, 32);
    nf += __shfl_xor(nf, 16); nf += __shfl_xor(nf, 32);
    ng += __shfl_xor(ng, 16); ng += __shfl_xor(ng, 32);
    if (lane < 16) {
      atomicAdd(&sred[0 * 64 + in * 16 + lane], d);
      atomicAdd(&sred[1 * 64 + in * 16 + lane], nf);
      atomicAdd(&sred[2 * 64 + in * 16 + lane], ng);
    }
  }
  __syncthreads();
  if (t < 64) {
    float d = sred[t], nf = sred[64 + t], ng = sred[128 + t];
    Sout[(size_t)b * PIX + p0 + t] = d / (sqrtf(nf) * sqrtf(ng));
  }
}

// ---------------------------------------------------------------------------
// Kernel 2b: EE/HH gemms fused with the blend: out = S_n*EE + (1-S_n)*HH.
// EE/HH never touch global memory (saves 268 MB round-trip vs separate
// blend kernel); fp32 out written directly from the accumulators.
// ---------------------------------------------------------------------------
__global__ __launch_bounds__(256, 2) void k_gemm2(const unsigned short* __restrict__ xcm,
                                                  const unsigned short* __restrict__ wbf,
                                                  const float* __restrict__ bEE,
                                                  const float* __restrict__ bHH,
                                                  const float* __restrict__ S,
                                                  const float* __restrict__ mm,
                                                  float* __restrict__ out) {
  int blk  = blockIdx.x;
  int b    = blk >> 8;
  int pt   = blk & 255;
  int p0   = pt * 64;
  int t    = threadIdx.x;
  int wv   = t >> 6;
  int lane = t & 63;
  int col  = lane & 15;
  int q    = lane >> 4;
  int mbase = wv * 64;

  __shared__ __align__(16) unsigned short xt[5][2048];   // 20 KB: 5 X buffers
  unsigned xbase = (unsigned)(unsigned long long)&xt[0][0];

  const unsigned short* Xt = xcm + (((size_t)(b * 256 + pt)) << 14);

  float4v aE[4][4], aH[4][4];

  gemm_pipe(Xt + 2 * TSZ, wbf + 2 * 65536, &xt[0][0], xbase, mbase, lane, t, aE);
  gemm_pipe(Xt + 3 * TSZ, wbf + 3 * 65536, &xt[0][0], xbase, mbase, lane, t, aH);

  float mn = mm[b * 2], mx = mm[b * 2 + 1];
  float inv = 1.f / (mx - mn);
  float sn[4];
  #pragma unroll
  for (int in = 0; in < 4; ++in)
    sn[in] = (S[(size_t)b * PIX + p0 + in * 16 + col] - mn) * inv;

  #pragma unroll
  for (int im = 0; im < 4; ++im) {
    float4v bvE = *(const float4v*)(bEE + mbase + im * 16 + q * 4);
    float4v bvH = *(const float4v*)(bHH + mbase + im * 16 + q * 4);
    #pragma unroll
    for (int in = 0; in < 4; ++in)
      #pragma unroll
      for (int r = 0; r < 4; ++r) {
        int m = mbase + im * 16 + q * 4 + r;
        float e = aE[in][im][r] + bvE[r];
        float h = aH[in][im][r] + bvH[r];
        out[((size_t)(b * 256 + m)) * PIX + p0 + in * 16 + col] = h + sn[in] * (e - h);
      }
  }
}

// ---------------------------------------------------------------------------
// Kernel 3: per-batch min/max of S (one block per batch)
// ---------------------------------------------------------------------------
__global__ __launch_bounds__(256) void k_minmax(const float* __restrict__ S,
                                                float* __restrict__ mm) {
  int b = blockIdx.x, t = threadIdx.x;
  const float* sp = S + (size_t)b * PIX;
  float mn = 3.0e38f, mx = -3.0e38f;
  for (int i = t; i < PIX; i += 256) { float v = sp[i]; mn = fminf(mn, v); mx = fmaxf(mx, v); }
  #pragma unroll
  for (int o = 32; o >= 1; o >>= 1) {
    mn = fminf(mn, __shfl_xor(mn, o));
    mx = fmaxf(mx, __shfl_xor(mx, o));
  }
  __shared__ float smn[4], smx[4];
  if ((t & 63) == 0) { smn[t >> 6] = mn; smx[t >> 6] = mx; }
  __syncthreads();
  if (t == 0) {
    mn = fminf(fminf(smn[0], smn[1]), fminf(smn[2], smn[3]));
    mx = fmaxf(fmaxf(smx[0], smx[1]), fmaxf(smx[2], smx[3]));
    mm[b * 2] = mn; mm[b * 2 + 1] = mx;
  }
}

// ---------------------------------------------------------------------------
// Workspace layout (bytes):
//   0          : xcm   4 tensors bf16 (tiled)    = 268,435,456
//   268435456  : wbf   4x256x256 bf16 (packed)   =     524,288
//   268959744  : S     fp32 8x16384              =     524,288
//   269484032  : mm    fp32 8x2                  =          64
// total ~269.5 MB
// ---------------------------------------------------------------------------
extern "C" void kernel_launch(void* const* d_in, const int* in_sizes, int n_in,
                              void* d_out, int out_size, void* d_ws, size_t ws_size,
                              hipStream_t stream) {
  const float* front = (const float*)d_in[0];
  const float* back  = (const float*)d_in[1];
  // d_in[2] = mask (unused by reference)
  const float* we = (const float*)d_in[3];
  const float* be = (const float*)d_in[4];
  const float* wf = (const float*)d_in[5];
  const float* bf = (const float*)d_in[6];
  const float* wg = (const float*)d_in[7];
  const float* bg = (const float*)d_in[8];
  const float* wh = (const float*)d_in[9];
  const float* bh = (const float*)d_in[10];

  char* ws = (char*)d_ws;
  unsigned short* xcm  = (unsigned short*)(ws);
  unsigned short* wbf  = (unsigned short*)(ws + 268435456);
  float*          S    = (float*)(ws + 268959744);
  float*          mm   = (float*)(ws + 269484032);
  float*          out  = (float*)d_out;

  k_prep  <<<1024,  256, 0, stream>>>(we, wf, wg, wh, wbf);
  k_stats <<<16384, 256, 0, stream>>>(front, back, xcm);
  k_gemm1 <<<2048,  256, 0, stream>>>(xcm, wbf, bf, bg, S);
  k_minmax<<<8,     256, 0, stream>>>(S, mm);
  k_gemm2 <<<2048,  256, 0, stream>>>(xcm, wbf, be, bh, S, mm, out);
}

// Round 5
// 517.431 us; speedup vs baseline: 1.3731x; 1.0103x over previous
//
#include <hip/hip_runtime.h>
#include <math.h>

// Problem constants: B=8, C=256, H=W=128
#define PIX 16384                       // H*W
#define TSZ ((size_t)33554432)          // 8*256*16384 elements per tensor

typedef __attribute__((ext_vector_type(8))) short  short8;   // 8 x bf16 (4 VGPRs)
typedef __attribute__((ext_vector_type(4))) float  float4v;
typedef __attribute__((ext_vector_type(4))) unsigned int uint4v;
typedef __attribute__((ext_vector_type(2))) unsigned int uint2v;

__device__ __forceinline__ unsigned short f2bf(float x) {
  unsigned int u = __float_as_uint(x);
  u += 0x7fffu + ((u >> 16) & 1u);      // round-to-nearest-even
  return (unsigned short)(u >> 16);
}
__device__ __forceinline__ float bf2f(unsigned short h) {
  return __uint_as_float(((unsigned int)h) << 16);
}
// pack two fp32 -> (bf16(hi)<<16)|bf16(lo) via v_perm_b32
__device__ __forceinline__ unsigned int pack_bf2(float lo, float hi) {
  unsigned int ul = __float_as_uint(lo); ul += 0x7fffu + ((ul >> 16) & 1u);
  unsigned int uh = __float_as_uint(hi); uh += 0x7fffu + ((uh >> 16) & 1u);
  return __builtin_amdgcn_perm(uh, ul, 0x07060302u);  // [ul.b2,ul.b3,uh.b2,uh.b3]
}

#define SB0   __builtin_amdgcn_sched_barrier(0)
#define BARR  __builtin_amdgcn_s_barrier()
#define LGKM0 asm volatile("s_waitcnt lgkmcnt(0)" ::: "memory")
#define VMC(n) asm volatile("s_waitcnt vmcnt(" #n ")" ::: "memory")

// ---------------------------------------------------------------------------
// Kernel 0: weights -> bf16, PACKED for lane-linear 1KB wave loads.
// Layout (shorts): wpk[g][i=kstep(8)][wv(4)][im(4)][lane(64)][e(8)]
//   lane=(q<<4)|col;  m = wv*64+im*16+col;  k = i*32+q*8+e
// Conv order: 0=FF(wf), 1=GG(wg), 2=EE(we), 3=HH(wh)
// ---------------------------------------------------------------------------
__global__ __launch_bounds__(256) void k_prep(const float* __restrict__ we,
                                              const float* __restrict__ wf,
                                              const float* __restrict__ wg,
                                              const float* __restrict__ wh,
                                              unsigned short* __restrict__ wbf) {
  int idx = blockIdx.x * 256 + threadIdx.x;      // 0 .. 262143
  int g = idx >> 16, within = idx & 65535;
  const float* src = (g == 0) ? wf : (g == 1) ? wg : (g == 2) ? we : wh;
  int e    = within & 7;
  int lane = (within >> 3) & 63;
  int im   = (within >> 9) & 3;
  int wv   = (within >> 11) & 3;
  int i    = within >> 13;
  int col = lane & 15, q = lane >> 4;
  int m = wv * 64 + im * 16 + col;
  int k = i * 32 + q * 8 + e;
  wbf[idx] = f2bf(src[m * 256 + k]);
}

// ---------------------------------------------------------------------------
// Kernel 1: 7x7 patch stats (zero-padded box sums), normalization, adain.
// R5: obI staging + copy-out removed (direct coalesced uint4 stores from the
// horizontal phase -- tiled xcm makes them 64B-segment coalesced); vsp gets
// 3 zero-padded columns each side (no bounds predication); __syncthreads
// replaced by lgkmcnt(0)+s_barrier so global loads/stores stay in flight
// across barriers. LDS 36.3->28.9 KB => 5 blocks/CU.
// Output TILED: xcm[tens][b][pt(256)][k=c(256)][px(64)] bf16.
// ---------------------------------------------------------------------------
__global__ __launch_bounds__(256, 5) void k_stats(const float* __restrict__ front,
                                                  const float* __restrict__ back,
                                                  unsigned short* __restrict__ xcm) {
  int blk = blockIdx.x;
  int s   = blk & 7;            // strip (16 rows)
  int c   = (blk >> 3) & 255;
  int b   = blk >> 11;
  int t   = threadIdx.x;
  int r0  = s * 16;

  __shared__ float  xs[22 * 129];          // 11.35 KB
  __shared__ float2 vspD[16 * 137];        // 17.54 KB; cols 0..133 = actual -3..130

  size_t planeOff = ((size_t)(b * 256 + c)) * PIX;

  float meanR[8], sdR[8];       // back stats, phase0 -> phase1 carry

  #pragma unroll 1
  for (int phase = 0; phase < 2; ++phase) {     // 0 = back, 1 = front
    const float* src = (phase == 0 ? back : front) + planeOff;
    // ---- load 22 rows (3-halo, zero outside [0,128)) x 128 cols, float4 ----
    #pragma unroll
    for (int i = 0; i < 3; ++i) {
      int idx = t + i * 256;                     // 704 = 22*32 float4s
      if (idx < 704) {
        int l = idx >> 5, cv = (idx & 31) * 4;
        int g = r0 - 3 + l;
        float4v v = {0.f, 0.f, 0.f, 0.f};
        if (g >= 0 && g < 128) v = *(const float4v*)(src + g * 128 + cv);
        xs[l * 129 + cv]     = v[0];
        xs[l * 129 + cv + 1] = v[1];
        xs[l * 129 + cv + 2] = v[2];
        xs[l * 129 + cv + 3] = v[3];
      }
    }
    LGKM0; BARR;
    // ---- vertical 7-tap sliding box sums of (x, x^2) -> float2 (padded) ----
    {
      int col = t & 127;
      int rg  = (t >> 7) * 8;                    // 8 output rows per thread
      float sm = 0.f, s2 = 0.f;
      #pragma unroll
      for (int j = 0; j < 7; ++j) { float v = xs[(rg + j) * 129 + col]; sm += v; s2 = fmaf(v, v, s2); }
      vspD[rg * 137 + col + 3] = make_float2(sm, s2);
      #pragma unroll
      for (int o = 1; o < 8; ++o) {
        float vn = xs[(rg + o + 6) * 129 + col];
        float vo = xs[(rg + o - 1) * 129 + col];
        sm += vn - vo;
        s2 += vn * vn - vo * vo;
        vspD[(rg + o) * 137 + col + 3] = make_float2(sm, s2);
      }
      // zero pads: array cols 0,1,2 and 131,132,133 for all 16 rows
      if (t < 96) {
        int rr = t & 15;
        int pc = t >> 4;                         // 0..5
        int ac = (pc < 3) ? pc : 128 + pc;       // 0,1,2,131,132,133
        vspD[rr * 137 + ac] = make_float2(0.f, 0.f);
      }
    }
    LGKM0; BARR;
    // ---- horizontal 7-tap sliding window + finalize + DIRECT stores ----
    {
      int r  = t & 15;
      int c0 = (t >> 4) * 8;                     // 8 output cols per thread
      float2 w[14];
      #pragma unroll
      for (int i = 0; i < 14; ++i) w[i] = vspD[r * 137 + c0 + i];
      float sm = 0.f, s2 = 0.f;
      #pragma unroll
      for (int i = 0; i < 7; ++i) { sm += w[i].x; s2 += w[i].y; }
      float nrmv[8], hv[8];
      #pragma unroll
      for (int o = 0; o < 8; ++o) {
        float mean = sm * (1.f / 49.f);
        float var  = (s2 - sm * mean) * (1.f / 48.f);   // (s2 - s^2/49)/48
        var = var > 0.f ? var : 0.f;
        float sd = __builtin_amdgcn_sqrtf(var);
        float x  = xs[(r + 3) * 129 + c0 + o];
        float nrm = (x - mean) * __builtin_amdgcn_rcpf(sd + 1e-8f);
        if (phase == 0) { meanR[o] = mean; sdR[o] = sd; hv[o] = x; }
        else            { hv[o] = nrm * sdR[o] + meanR[o]; }
        nrmv[o] = nrm;
        if (o < 7) { sm += w[o + 7].x - w[o].x; s2 += w[o + 7].y - w[o].y; }
      }
      uint4v nv  = (uint4v){pack_bf2(nrmv[0], nrmv[1]), pack_bf2(nrmv[2], nrmv[3]),
                            pack_bf2(nrmv[4], nrmv[5]), pack_bf2(nrmv[6], nrmv[7])};
      uint4v hvv = (uint4v){pack_bf2(hv[0], hv[1]), pack_bf2(hv[2], hv[3]),
                            pack_bf2(hv[4], hv[5]), pack_bf2(hv[6], hv[7])};
      // tiled store: p -> (pt=p>>6, pxi=p&63); addr = ((b*256+pt)*256+c)*64+pxi
      int p = (r0 + r) * 128 + c0;
      size_t gb2 = (((size_t)(b * 256 + (p >> 6))) * 256 + c) * 64 + (p & 63);
      int tn0 = (phase == 0) ? 1 : 0;
      int tn1 = (phase == 0) ? 3 : 2;
      *(uint4v*)(xcm + (size_t)tn0 * TSZ + gb2) = nv;
      *(uint4v*)(xcm + (size_t)tn1 * TSZ + gb2) = hvv;
    }
    LGKM0; BARR;   // all xs/vsp reads done; next phase may overwrite
  }
}

// ---------------------------------------------------------------------------
// GEMM machinery (R3's counted-vmcnt 5-buffer pipeline, packed operands).
// ---------------------------------------------------------------------------
__device__ __forceinline__ void stage_tile(const unsigned short* __restrict__ Xt,
                                           int k0, int t,
                                           unsigned short* dst) {
  // LDS 16B-chunk t holds subtile element: k = (t>>5)*4 + ((t&7)>>1),
  // px = ((t>>3)&3)*16 + (t&1)*8.  Source tile is contiguous [k][px] 4KB.
  int kk = ((t >> 5) << 2) + ((t & 7) >> 1);
  int px = (((t >> 3) & 3) << 4) + ((t & 1) << 3);
  const unsigned short* src = Xt + (size_t)(k0 << 6) + (kk << 6) + px;
  typedef const __attribute__((address_space(1))) unsigned int GUI;
  typedef __attribute__((address_space(3))) unsigned int LUI;
  __builtin_amdgcn_global_load_lds((GUI*)(unsigned long long)src,
                                   (LUI*)(unsigned)(unsigned long long)(dst + t * 8),
                                   16, 0, 0);
}

// packed weights: af[S][im] <- Wr + I*8192 + im*512  (lane-linear 1KB/instr)
#define LOADA(S, I) {                                           \
  af[S][0] = *(const short8*)(Wr + (I) * 8192 + 0 * 512);       \
  af[S][1] = *(const short8*)(Wr + (I) * 8192 + 1 * 512);       \
  af[S][2] = *(const short8*)(Wr + (I) * 8192 + 2 * 512);       \
  af[S][3] = *(const short8*)(Wr + (I) * 8192 + 3 * 512); }

#define TR8(O0,O1,O2,O3,O4,O5,O6,O7)                                              \
  asm volatile("ds_read_b64_tr_b16 %0, %1 offset:" #O0 : "=v"(r0) : "v"(tra));    \
  asm volatile("ds_read_b64_tr_b16 %0, %1 offset:" #O1 : "=v"(r1) : "v"(tra));    \
  asm volatile("ds_read_b64_tr_b16 %0, %1 offset:" #O2 : "=v"(r2) : "v"(tra));    \
  asm volatile("ds_read_b64_tr_b16 %0, %1 offset:" #O3 : "=v"(r3) : "v"(tra));    \
  asm volatile("ds_read_b64_tr_b16 %0, %1 offset:" #O4 : "=v"(r4) : "v"(tra));    \
  asm volatile("ds_read_b64_tr_b16 %0, %1 offset:" #O5 : "=v"(r5) : "v"(tra));    \
  asm volatile("ds_read_b64_tr_b16 %0, %1 offset:" #O6 : "=v"(r6) : "v"(tra));    \
  asm volatile("ds_read_b64_tr_b16 %0, %1 offset:" #O7 : "=v"(r7) : "v"(tra));

#define DOMFMA(MS) {                                                        \
  union BU { unsigned u[4]; short8 s; } bu0, bu1, bu2, bu3;                 \
  bu0.u[0]=r0[0]; bu0.u[1]=r0[1]; bu0.u[2]=r1[0]; bu0.u[3]=r1[1];           \
  bu1.u[0]=r2[0]; bu1.u[1]=r2[1]; bu1.u[2]=r3[0]; bu1.u[3]=r3[1];           \
  bu2.u[0]=r4[0]; bu2.u[1]=r4[1]; bu2.u[2]=r5[0]; bu2.u[3]=r5[1];           \
  bu3.u[0]=r6[0]; bu3.u[1]=r6[1]; bu3.u[2]=r7[0]; bu3.u[3]=r7[1];           \
  short8 bv0 = bu0.s, bv1 = bu1.s, bv2 = bu2.s, bv3 = bu3.s;                \
  _Pragma("unroll")                                                         \
  for (int im = 0; im < 4; ++im) {                                          \
    acc[0][im] = __builtin_amdgcn_mfma_f32_16x16x32_bf16(af[MS][im], bv0, acc[0][im], 0, 0, 0); \
    acc[1][im] = __builtin_amdgcn_mfma_f32_16x16x32_bf16(af[MS][im], bv1, acc[1][im], 0, 0, 0); \
    acc[2][im] = __builtin_amdgcn_mfma_f32_16x16x32_bf16(af[MS][im], bv2, acc[2][im], 0, 0, 0); \
    acc[3][im] = __builtin_amdgcn_mfma_f32_16x16x32_bf16(af[MS][im], bv3, acc[3][im], 0, 0, 0); \
  } }

// one K-step: optional stage (depth-3), optional A prefetch (2 ahead),
// counted vmcnt, barrier, tr-reads of buf i, MFMA.
#define GSTEP(VN, DOSTAGE, K0, SLOT, DOA, AS, AI, MS, O0,O1,O2,O3,O4,O5,O6,O7) \
  SB0;                                                                          \
  if (DOSTAGE) stage_tile(X, K0, t, xt + (SLOT) * 2048);                        \
  SB0;                                                                          \
  if (DOA) LOADA(AS, AI);                                                       \
  SB0;                                                                          \
  VMC(VN);                                                                      \
  SB0; BARR; SB0;                                                               \
  TR8(O0,O1,O2,O3,O4,O5,O6,O7);                                                 \
  LGKM0; SB0;                                                                   \
  DOMFMA(MS);

__device__ __forceinline__ void gemm_pipe(const unsigned short* __restrict__ X,
                                          const unsigned short* __restrict__ Wm,
                                          unsigned short* xt, unsigned xbase,
                                          int mbase, int lane, int t,
                                          float4v acc[4][4]) {
  unsigned tra = xbase + (unsigned)((((lane >> 4)) << 10) + ((lane & 15) << 3));
  // packed weights: Wr = Wm + wv*2048 + lane*8
  const unsigned short* __restrict__ Wr = Wm + ((mbase >> 6) << 11) + lane * 8;

  short8 af[3][4];
  uint2v r0, r1, r2, r3, r4, r5, r6, r7;

  #pragma unroll
  for (int in = 0; in < 4; ++in)
    #pragma unroll
    for (int im = 0; im < 4; ++im)
      acc[in][im] = (float4v){0.f, 0.f, 0.f, 0.f};

  // top barrier: all waves done reading slots of the previous gemm
  SB0; BARR; SB0;
  stage_tile(X,  0, t, xt + 0 * 2048);
  stage_tile(X, 32, t, xt + 1 * 2048);
  stage_tile(X, 64, t, xt + 2 * 2048);
  SB0;
  LOADA(0, 0);
  SB0;
  LOADA(1, 1);
  SB0;

  //     VN  st  K0  slot  A  AS AI MS   tr offsets (slot*4096 + subtile)
  GSTEP( 9,  1,  96,  3,   1, 2, 2, 0,      0,  512,  128,  640,  256,  768,  384,  896)
  GSTEP(10,  1, 128,  4,   1, 0, 3, 1,   4096, 4608, 4224, 4736, 4352, 4864, 4480, 4992)
  GSTEP(10,  1, 160,  0,   1, 1, 4, 2,   8192, 8704, 8320, 8832, 8448, 8960, 8576, 9088)
  GSTEP(10,  1, 192,  1,   1, 2, 5, 0,  12288,12800,12416,12928,12544,13056,12672,13184)
  GSTEP(10,  1, 224,  2,   1, 0, 6, 1,  16384,16896,16512,17024,16640,17152,16768,17280)
  GSTEP( 9,  0,   0,  0,   1, 1, 7, 2,      0,  512,  128,  640,  256,  768,  384,  896)
  GSTEP( 4,  0,   0,  0,   0, 0, 0, 0,   4096, 4608, 4224, 4736, 4352, 4864, 4480, 4992)
  GSTEP( 0,  0,   0,  0,   0, 0, 0, 1,   8192, 8704, 8320, 8832, 8448, 8960, 8576, 9088)
}

// ---------------------------------------------------------------------------
// Kernel 2a: FF/GG gemms -> cosine similarity S.
// ---------------------------------------------------------------------------
__global__ __launch_bounds__(256, 2) void k_gemm1(const unsigned short* __restrict__ xcm,
                                                  const unsigned short* __restrict__ wbf,
                                                  const float* __restrict__ bFF,
                                                  const float* __restrict__ bGG,
                                                  float* __restrict__ Sout) {
  int blk  = blockIdx.x;
  int b    = blk >> 8;
  int pt   = blk & 255;
  int p0   = pt * 64;
  int t    = threadIdx.x;
  int wv   = t >> 6;
  int lane = t & 63;
  int q    = lane >> 4;
  int mbase = wv * 64;

  __shared__ __align__(16) unsigned short xt[5][2048];   // 20 KB: 5 X buffers
  __shared__ float sred[3 * 64];       // dot, |F|^2, |G|^2 per pixel
  if (t < 192) sred[t] = 0.f;
  __syncthreads();
  unsigned xbase = (unsigned)(unsigned long long)&xt[0][0];

  // contiguous X tile base for this (b, pt): xcm[tens][b][pt][k][px]
  const unsigned short* Xt = xcm + (((size_t)(b * 256 + pt)) << 14);

  float4v aF[4][4], aG[4][4];

  gemm_pipe(Xt + 0 * TSZ, wbf + 0 * 65536, &xt[0][0], xbase, mbase, lane, t, aF);
  gemm_pipe(Xt + 1 * TSZ, wbf + 1 * 65536, &xt[0][0], xbase, mbase, lane, t, aG);
  #pragma unroll
  for (int im = 0; im < 4; ++im) {
    float4v bvF = *(const float4v*)(bFF + mbase + im * 16 + q * 4);
    float4v bvG = *(const float4v*)(bGG + mbase + im * 16 + q * 4);
    #pragma unroll
    for (int in = 0; in < 4; ++in) { aF[in][im] += bvF; aG[in][im] += bvG; }
  }
  // cosine partials: lane-local over 16 m's, then quad shuffle, then LDS
  #pragma unroll
  for (int in = 0; in < 4; ++in) {
    float d = 0.f, nf = 0.f, ng = 0.f;
    #pragma unroll
    for (int im = 0; im < 4; ++im)
      #pragma unroll
      for (int r = 0; r < 4; ++r) {
        float f = aF[in][im][r], g = aG[in][im][r];
        d += f * g; nf += f * f; ng += g * g;
      }
    d  += __shfl_xor(d, 16);  d  += __shfl_xor(d, 32);
    nf += __shfl_xor(nf, 16); nf += __shfl_xor(nf, 32);
    ng += __shfl_xor(ng, 16); ng += __shfl_xor(ng, 32);
    if (lane < 16) {
      atomicAdd(&sred[0 * 64 + in * 16 + lane], d);
      atomicAdd(&sred[1 * 64 + in * 16 + lane], nf);
      atomicAdd(&sred[2 * 64 + in * 16 + lane], ng);
    }
  }
  __syncthreads();
  if (t < 64) {
    float d = sred[t], nf = sred[64 + t], ng = sred[128 + t];
    Sout[(size_t)b * PIX + p0 + t] = d / (sqrtf(nf) * sqrtf(ng));
  }
}

// ---------------------------------------------------------------------------
// Kernel 2b: EE/HH gemms fused with the blend: out = S_n*EE + (1-S_n)*HH.
// ---------------------------------------------------------------------------
__global__ __launch_bounds__(256, 2) void k_gemm2(const unsigned short* __restrict__ xcm,
                                                  const unsigned short* __restrict__ wbf,
                                                  const float* __restrict__ bEE,
                                                  const float* __restrict__ bHH,
                                                  const float* __restrict__ S,
                                                  const float* __restrict__ mm,
                                                  float* __restrict__ out) {
  int blk  = blockIdx.x;
  int b    = blk >> 8;
  int pt   = blk & 255;
  int p0   = pt * 64;
  int t    = threadIdx.x;
  int wv   = t >> 6;
  int lane = t & 63;
  int col  = lane & 15;
  int q    = lane >> 4;
  int mbase = wv * 64;

  __shared__ __align__(16) unsigned short xt[5][2048];   // 20 KB: 5 X buffers
  unsigned xbase = (unsigned)(unsigned long long)&xt[0][0];

  const unsigned short* Xt = xcm + (((size_t)(b * 256 + pt)) << 14);

  float4v aE[4][4], aH[4][4];

  gemm_pipe(Xt + 2 * TSZ, wbf + 2 * 65536, &xt[0][0], xbase, mbase, lane, t, aE);
  gemm_pipe(Xt + 3 * TSZ, wbf + 3 * 65536, &xt[0][0], xbase, mbase, lane, t, aH);

  float mn = mm[b * 2], mx = mm[b * 2 + 1];
  float inv = 1.f / (mx - mn);
  float sn[4];
  #pragma unroll
  for (int in = 0; in < 4; ++in)
    sn[in] = (S[(size_t)b * PIX + p0 + in * 16 + col] - mn) * inv;

  #pragma unroll
  for (int im = 0; im < 4; ++im) {
    float4v bvE = *(const float4v*)(bEE + mbase + im * 16 + q * 4);
    float4v bvH = *(const float4v*)(bHH + mbase + im * 16 + q * 4);
    #pragma unroll
    for (int in = 0; in < 4; ++in)
      #pragma unroll
      for (int r = 0; r < 4; ++r) {
        int m = mbase + im * 16 + q * 4 + r;
        float e = aE[in][im][r] + bvE[r];
        float h = aH[in][im][r] + bvH[r];
        out[((size_t)(b * 256 + m)) * PIX + p0 + in * 16 + col] = h + sn[in] * (e - h);
      }
  }
}

// ---------------------------------------------------------------------------
// Kernel 3: per-batch min/max of S (one block per batch)
// ---------------------------------------------------------------------------
__global__ __launch_bounds__(256) void k_minmax(const float* __restrict__ S,
                                                float* __restrict__ mm) {
  int b = blockIdx.x, t = threadIdx.x;
  const float* sp = S + (size_t)b * PIX;
  float mn = 3.0e38f, mx = -3.0e38f;
  for (int i = t; i < PIX; i += 256) { float v = sp[i]; mn = fminf(mn, v); mx = fmaxf(mx, v); }
  #pragma unroll
  for (int o = 32; o >= 1; o >>= 1) {
    mn = fminf(mn, __shfl_xor(mn, o));
    mx = fmaxf(mx, __shfl_xor(mx, o));
  }
  __shared__ float smn[4], smx[4];
  if ((t & 63) == 0) { smn[t >> 6] = mn; smx[t >> 6] = mx; }
  __syncthreads();
  if (t == 0) {
    mn = fminf(fminf(smn[0], smn[1]), fminf(smn[2], smn[3]));
    mx = fmaxf(fmaxf(smx[0], smx[1]), fmaxf(smx[2], smx[3]));
    mm[b * 2] = mn; mm[b * 2 + 1] = mx;
  }
}

// ---------------------------------------------------------------------------
// Workspace layout (bytes):
//   0          : xcm   4 tensors bf16 (tiled)    = 268,435,456
//   268435456  : wbf   4x256x256 bf16 (packed)   =     524,288
//   268959744  : S     fp32 8x16384              =     524,288
//   269484032  : mm    fp32 8x2                  =          64
// total ~269.5 MB
// ---------------------------------------------------------------------------
extern "C" void kernel_launch(void* const* d_in, const int* in_sizes, int n_in,
                              void* d_out, int out_size, void* d_ws, size_t ws_size,
                              hipStream_t stream) {
  const float* front = (const float*)d_in[0];
  const float* back  = (const float*)d_in[1];
  // d_in[2] = mask (unused by reference)
  const float* we = (const float*)d_in[3];
  const float* be = (const float*)d_in[4];
  const float* wf = (const float*)d_in[5];
  const float* bf = (const float*)d_in[6];
  const float* wg = (const float*)d_in[7];
  const float* bg = (const float*)d_in[8];
  const float* wh = (const float*)d_in[9];
  const float* bh = (const float*)d_in[10];

  char* ws = (char*)d_ws;
  unsigned short* xcm  = (unsigned short*)(ws);
  unsigned short* wbf  = (unsigned short*)(ws + 268435456);
  float*          S    = (float*)(ws + 268959744);
  float*          mm   = (float*)(ws + 269484032);
  float*          out  = (float*)d_out;

  k_prep  <<<1024,  256, 0, stream>>>(we, wf, wg, wh, wbf);
  k_stats <<<16384, 256, 0, stream>>>(front, back, xcm);
  k_gemm1 <<<2048,  256, 0, stream>>>(xcm, wbf, bf, bg, S);
  k_minmax<<<8,     256, 0, stream>>>(S, mm);
  k_gemm2 <<<2048,  256, 0, stream>>>(xcm, wbf, be, bh, S, mm, out);
}